// Round 1
// baseline (2053.277 us; speedup 1.0000x reference)
//
#include <hip/hip_runtime.h>
#include <hip/hip_bf16.h>
#include <cstdint>
#include <cstddef>

#define N_NODES 100000
#define N_EDGES 1600000
#define EMBD 128
#define HID 256
#define N_GRAPHS 128

// ---------------- CSR build ----------------
__global__ void k_indeg(const int* __restrict__ dst, int* __restrict__ indeg) {
  int e = blockIdx.x * 256 + threadIdx.x;
  if (e < N_EDGES) atomicAdd(&indeg[dst[e]], 1);
}

__global__ void k_dis(const int* __restrict__ indeg, float* __restrict__ dis) {
  int i = blockIdx.x * 256 + threadIdx.x;
  if (i < N_NODES) dis[i] = rsqrtf((float)(indeg[i] + 1));
}

__global__ __launch_bounds__(1024)
void k_scan(const int* __restrict__ indeg, int* __restrict__ off, int* __restrict__ cursor) {
  __shared__ int s[1024];
  const int tid = threadIdx.x;
  int carry = 0;
  for (int base = 0; base < N_NODES; base += 1024) {
    int i = base + tid;
    int v = (i < N_NODES) ? indeg[i] : 0;
    __syncthreads();              // protect s[] from previous chunk's readers
    s[tid] = v;
    __syncthreads();
    #pragma unroll
    for (int ofs = 1; ofs < 1024; ofs <<= 1) {
      int t2 = (tid >= ofs) ? s[tid - ofs] : 0;
      __syncthreads();
      s[tid] += t2;
      __syncthreads();
    }
    int excl = s[tid] - v + carry;   // exclusive within chunk + carry
    if (i < N_NODES) { off[i] = excl; cursor[i] = excl; }
    carry += s[1023];                // same value in all threads
  }
  if (tid == 0) off[N_NODES] = carry;
}

__global__ void k_fill(const int* __restrict__ src, const int* __restrict__ dst,
                       int* __restrict__ cursor, int* __restrict__ csr) {
  int e = blockIdx.x * 256 + threadIdx.x;
  if (e < N_EDGES) {
    int p = atomicAdd(&cursor[dst[e]], 1);
    csr[p] = src[e];
  }
}

// ---------------- embedding gather ----------------
__global__ void k_embed(const int* __restrict__ ids, const float* __restrict__ emb,
                        float* __restrict__ x) {
  int i = blockIdx.x * 256 + threadIdx.x;    // over N_NODES*32 float4s
  int n = i >> 5, f = i & 31;
  ((float4*)x)[i] = ((const float4*)emb)[ids[n] * 32 + f];
}

// ---------------- normalized aggregation (gather, CSR) ----------------
// agg[i] = dis[i] * ( dis[i]*x[i] + sum_{e: dst=i} dis[src]*x[src] )
template<int V> struct VecSel;
template<> struct VecSel<2> { typedef float type __attribute__((ext_vector_type(2))); };
template<> struct VecSel<4> { typedef float type __attribute__((ext_vector_type(4))); };

template<int H>
__global__ __launch_bounds__(256)
void k_agg(const float* __restrict__ x, const float* __restrict__ dis,
           const int* __restrict__ off, const int* __restrict__ csr,
           float* __restrict__ agg) {
  constexpr int V = H / 64;                  // floats per lane
  typedef typename VecSel<V>::type fv;
  const int lane = threadIdx.x & 63;
  const int node = blockIdx.x * 4 + (threadIdx.x >> 6);  // wave per node
  const float di = dis[node];
  const fv* xi = (const fv*)(x + (size_t)node * H) + lane;
  fv acc = di * (*xi);
  const int e0 = off[node], e1 = off[node + 1];
  for (int e = e0; e < e1; ++e) {
    int s = csr[e];
    float ds = dis[s];
    const fv* xs = (const fv*)(x + (size_t)s * H) + lane;
    acc += ds * (*xs);
  }
  fv* ao = (fv*)(agg + (size_t)node * H) + lane;
  *ao = di * acc;
}

// ---------------- f32 tiled GEMM: C[N,256] = relu(A[N,K] @ W[K,256] + b) ----------------
template<int K>
__global__ __launch_bounds__(256)
void k_gemm_relu(const float* __restrict__ A, const float* __restrict__ W,
                 const float* __restrict__ bias, float* __restrict__ C) {
  constexpr int BM = 128, BN = 128, BK = 16;
  __shared__ float sA[BK][BM];   // transposed A tile
  __shared__ float sB[BK][BN];
  const int tid = threadIdx.x;
  const int row0 = blockIdx.x * BM;
  const int col0 = blockIdx.y * BN;
  const int tx = tid & 15, ty = tid >> 4;
  // A staging: thread loads rows ra, ra+64 at k-offset ka (float4)
  const int ra = tid >> 2;            // 0..63
  const int ka = (tid & 3) * 4;       // 0,4,8,12
  // B staging: rows kb, kb+8; cols cb..cb+3
  const int kb = tid >> 5;            // 0..7
  const int cb = (tid & 31) * 4;      // 0..124

  float acc[8][8];
  #pragma unroll
  for (int i = 0; i < 8; ++i)
    #pragma unroll
    for (int j = 0; j < 8; ++j) acc[i][j] = 0.f;

  for (int kt = 0; kt < K; kt += BK) {
    #pragma unroll
    for (int h = 0; h < 2; ++h) {
      int r = ra + h * 64;
      int gr = row0 + r;
      float4 v = make_float4(0.f, 0.f, 0.f, 0.f);
      if (gr < N_NODES) v = *(const float4*)&A[(size_t)gr * K + kt + ka];
      sA[ka + 0][r] = v.x; sA[ka + 1][r] = v.y; sA[ka + 2][r] = v.z; sA[ka + 3][r] = v.w;
    }
    #pragma unroll
    for (int h = 0; h < 2; ++h) {
      int k = kb + h * 8;
      *(float4*)&sB[k][cb] = *(const float4*)&W[(size_t)(kt + k) * HID + col0 + cb];
    }
    __syncthreads();
    #pragma unroll
    for (int k = 0; k < BK; ++k) {
      float4 a0 = *(const float4*)&sA[k][ty * 4];
      float4 a1 = *(const float4*)&sA[k][ty * 4 + 64];
      float4 b0 = *(const float4*)&sB[k][tx * 4];
      float4 b1 = *(const float4*)&sB[k][tx * 4 + 64];
      float av[8] = {a0.x, a0.y, a0.z, a0.w, a1.x, a1.y, a1.z, a1.w};
      float bv[8] = {b0.x, b0.y, b0.z, b0.w, b1.x, b1.y, b1.z, b1.w};
      #pragma unroll
      for (int i = 0; i < 8; ++i)
        #pragma unroll
        for (int j = 0; j < 8; ++j)
          acc[i][j] = fmaf(av[i], bv[j], acc[i][j]);
    }
    __syncthreads();
  }

  float4 bb0 = *(const float4*)&bias[col0 + tx * 4];
  float4 bb1 = *(const float4*)&bias[col0 + tx * 4 + 64];
  float bv[8] = {bb0.x, bb0.y, bb0.z, bb0.w, bb1.x, bb1.y, bb1.z, bb1.w};
  #pragma unroll
  for (int i = 0; i < 8; ++i) {
    int r = row0 + ty * 4 + (i & 3) + (i >> 2) * 64;
    if (r >= N_NODES) continue;
    float4 o0, o1;
    o0.x = fmaxf(acc[i][0] + bv[0], 0.f);
    o0.y = fmaxf(acc[i][1] + bv[1], 0.f);
    o0.z = fmaxf(acc[i][2] + bv[2], 0.f);
    o0.w = fmaxf(acc[i][3] + bv[3], 0.f);
    o1.x = fmaxf(acc[i][4] + bv[4], 0.f);
    o1.y = fmaxf(acc[i][5] + bv[5], 0.f);
    o1.z = fmaxf(acc[i][6] + bv[6], 0.f);
    o1.w = fmaxf(acc[i][7] + bv[7], 0.f);
    *(float4*)&C[(size_t)r * HID + col0 + tx * 4] = o0;
    *(float4*)&C[(size_t)r * HID + col0 + tx * 4 + 64] = o1;
  }
}

// ---------------- pooling (mean + max per graph) ----------------
__device__ inline int lower_bound_i(const int* a, int n, int v) {
  int lo = 0, hi = n;
  while (lo < hi) { int m = (lo + hi) >> 1; if (a[m] < v) lo = m + 1; else hi = m; }
  return lo;
}

__global__ __launch_bounds__(256)
void k_pool(const float* __restrict__ x, const int* __restrict__ batch,
            float* __restrict__ g) {
  const int gi = blockIdx.x, t = threadIdx.x;
  const int start = lower_bound_i(batch, N_NODES, gi);
  const int end   = lower_bound_i(batch, N_NODES, gi + 1);
  float sum = 0.f, mx = 0.f;     // post-relu values >= 0; empty graph -> 0 matches where()
  #pragma unroll 4
  for (int n = start; n < end; ++n) {
    float v = x[(size_t)n * HID + t];
    sum += v; mx = fmaxf(mx, v);
  }
  int cnt = end - start;
  g[gi * 512 + t] = sum / (float)(cnt > 0 ? cnt : 1);
  g[gi * 512 + 256 + t] = mx;
}

// ---------------- classifier head ----------------
__global__ __launch_bounds__(256)
void k_cls(const float* __restrict__ g, const float* __restrict__ Wc1,
           const float* __restrict__ bc1, const float* __restrict__ Wc2,
           const float* __restrict__ bc2, float* __restrict__ out) {
  const int gi = blockIdx.x, t = threadIdx.x;
  __shared__ float sg[512];
  __shared__ float sh[256];
  sg[t] = g[gi * 512 + t];
  sg[256 + t] = g[gi * 512 + 256 + t];
  __syncthreads();
  float a = bc1[t];
  #pragma unroll 8
  for (int k = 0; k < 512; ++k) a = fmaf(sg[k], Wc1[k * HID + t], a);
  sh[t] = fmaxf(a, 0.f);
  __syncthreads();
  if (t < 2) {
    float o = bc2[t];
    for (int k = 0; k < 256; ++k) o = fmaf(sh[k], Wc2[k * 2 + t], o);
    out[gi * 2 + t] = o;
  }
}

// ---------------- launch ----------------
extern "C" void kernel_launch(void* const* d_in, const int* in_sizes, int n_in,
                              void* d_out, int out_size, void* d_ws, size_t ws_size,
                              hipStream_t stream) {
  const int*   x_ids = (const int*)d_in[0];
  const int*   ei    = (const int*)d_in[1];
  const int*   batch = (const int*)d_in[2];
  const float* emb   = (const float*)d_in[3];
  const float* W0 = (const float*)d_in[4];  const float* b0 = (const float*)d_in[5];
  const float* W1 = (const float*)d_in[6];  const float* b1 = (const float*)d_in[7];
  const float* W2 = (const float*)d_in[8];  const float* b2 = (const float*)d_in[9];
  const float* W3 = (const float*)d_in[10]; const float* b3 = (const float*)d_in[11];
  const float* Wc1 = (const float*)d_in[12]; const float* bc1 = (const float*)d_in[13];
  const float* Wc2 = (const float*)d_in[14]; const float* bc2 = (const float*)d_in[15];
  float* out = (float*)d_out;
  const int* src = ei;
  const int* dst = ei + N_EDGES;

  char* ws = (char*)d_ws;
  size_t o = 0;
  auto alloc = [&](size_t bytes) -> char* {
    char* p = ws + o; o += (bytes + 255) & ~(size_t)255; return p;
  };
  float* bufA  = (float*)alloc((size_t)N_NODES * HID * 4);   // x (ping)
  float* bufB  = (float*)alloc((size_t)N_NODES * HID * 4);   // agg (pong)
  float* dis   = (float*)alloc((size_t)N_NODES * 4);
  int*   indeg = (int*)  alloc((size_t)N_NODES * 4);
  int*   off   = (int*)  alloc((size_t)(N_NODES + 1) * 4);
  int*   cur   = (int*)  alloc((size_t)(N_NODES + 1) * 4);
  int*   csr   = (int*)  alloc((size_t)N_EDGES * 4);
  float* gf    = (float*)alloc((size_t)N_GRAPHS * 512 * 4);
  (void)ws_size; (void)in_sizes; (void)n_in; (void)out_size;

  hipMemsetAsync(indeg, 0, (size_t)N_NODES * 4, stream);
  k_indeg<<<N_EDGES / 256, 256, 0, stream>>>(dst, indeg);
  k_dis<<<(N_NODES + 255) / 256, 256, 0, stream>>>(indeg, dis);
  k_scan<<<1, 1024, 0, stream>>>(indeg, off, cur);
  k_fill<<<N_EDGES / 256, 256, 0, stream>>>(src, dst, cur, csr);
  k_embed<<<(N_NODES * 32) / 256, 256, 0, stream>>>(x_ids, emb, bufA);

  dim3 ggrid((N_NODES + 127) / 128, 2);
  // layer 0 (H_in = 128)
  k_agg<128><<<N_NODES / 4, 256, 0, stream>>>(bufA, dis, off, csr, bufB);
  k_gemm_relu<128><<<ggrid, 256, 0, stream>>>(bufB, W0, b0, bufA);
  // layers 1..3 (H_in = 256)
  k_agg<256><<<N_NODES / 4, 256, 0, stream>>>(bufA, dis, off, csr, bufB);
  k_gemm_relu<256><<<ggrid, 256, 0, stream>>>(bufB, W1, b1, bufA);
  k_agg<256><<<N_NODES / 4, 256, 0, stream>>>(bufA, dis, off, csr, bufB);
  k_gemm_relu<256><<<ggrid, 256, 0, stream>>>(bufB, W2, b2, bufA);
  k_agg<256><<<N_NODES / 4, 256, 0, stream>>>(bufA, dis, off, csr, bufB);
  k_gemm_relu<256><<<ggrid, 256, 0, stream>>>(bufB, W3, b3, bufA);

  k_pool<<<N_GRAPHS, 256, 0, stream>>>(bufA, batch, gf);
  k_cls<<<N_GRAPHS, 256, 0, stream>>>(gf, Wc1, bc1, Wc2, bc2, out);
}

// Round 2
// 1584.410 us; speedup vs baseline: 1.2959x; 1.2959x over previous
//
#include <hip/hip_runtime.h>
#include <hip/hip_bf16.h>
#include <cstdint>
#include <cstddef>

#define N_NODES 100000
#define N_EDGES 1600000
#define EMBD 128
#define HID 256
#define N_GRAPHS 128
#define NB_SCAN 98   // ceil(N_NODES/1024)

typedef short bf16x8 __attribute__((ext_vector_type(8)));
typedef float f32x4 __attribute__((ext_vector_type(4)));

// ---------------- CSR build ----------------
__global__ void k_indeg(const int* __restrict__ dst, int* __restrict__ indeg) {
  int e = blockIdx.x * 256 + threadIdx.x;
  if (e < N_EDGES) atomicAdd(&indeg[dst[e]], 1);
}

__global__ void k_dis(const int* __restrict__ indeg, float* __restrict__ dis) {
  int i = blockIdx.x * 256 + threadIdx.x;
  if (i < N_NODES) dis[i] = rsqrtf((float)(indeg[i] + 1));
}

__global__ __launch_bounds__(1024)
void k_scan1(const int* __restrict__ indeg, int* __restrict__ off, int* __restrict__ bsum) {
  __shared__ int s[1024];
  const int tid = threadIdx.x;
  int i = blockIdx.x * 1024 + tid;
  int v = (i < N_NODES) ? indeg[i] : 0;
  s[tid] = v; __syncthreads();
  #pragma unroll
  for (int ofs = 1; ofs < 1024; ofs <<= 1) {
    int t2 = (tid >= ofs) ? s[tid - ofs] : 0;
    __syncthreads();
    s[tid] += t2;
    __syncthreads();
  }
  if (i < N_NODES) off[i] = s[tid] - v;      // exclusive within block
  if (tid == 1023) bsum[blockIdx.x] = s[1023];
}

__global__ void k_scan2(int* __restrict__ bsum) {
  if (threadIdx.x == 0) {
    int a = 0;
    for (int i = 0; i < NB_SCAN; ++i) { int t = bsum[i]; bsum[i] = a; a += t; }
    bsum[NB_SCAN] = a;
  }
}

__global__ __launch_bounds__(1024)
void k_scan3(int* __restrict__ off, int* __restrict__ cur, const int* __restrict__ bsum) {
  int i = blockIdx.x * 1024 + threadIdx.x;
  if (i < N_NODES) { int v = off[i] + bsum[blockIdx.x]; off[i] = v; cur[i] = v; }
  if (i == 0) off[N_NODES] = bsum[NB_SCAN];
}

__global__ void k_fill(const int* __restrict__ src, const int* __restrict__ dst,
                       const float* __restrict__ dis,
                       int* __restrict__ cursor, int* __restrict__ csr,
                       float* __restrict__ csrd) {
  int e = blockIdx.x * 256 + threadIdx.x;
  if (e < N_EDGES) {
    int s = src[e];
    int p = atomicAdd(&cursor[dst[e]], 1);
    csr[p] = s;
    csrd[p] = dis[s];
  }
}

// ---------------- embedding gather ----------------
__global__ void k_embed(const int* __restrict__ ids, const float* __restrict__ emb,
                        float* __restrict__ x) {
  int i = blockIdx.x * 256 + threadIdx.x;    // over N_NODES*32 float4s
  int n = i >> 5, f = i & 31;
  ((float4*)x)[i] = ((const float4*)emb)[ids[n] * 32 + f];
}

// ---------------- W split/transpose prep: Wt_hi/lo[n][k] = split(W[k][n]) ----------------
__global__ void k_wsplit(const float* __restrict__ W, unsigned short* __restrict__ th,
                         unsigned short* __restrict__ tl, int K) {
  int i = blockIdx.x * 256 + threadIdx.x;    // over K*256
  int k = i >> 8, n = i & 255;
  float v = W[i];
  __hip_bfloat16 h = __float2bfloat16(v);
  float hf = __bfloat162float(h);
  __hip_bfloat16 l = __float2bfloat16(v - hf);
  th[n * K + k] = *(unsigned short*)&h;
  tl[n * K + k] = *(unsigned short*)&l;
}

// ---------------- normalized aggregation (gather, CSR), split-bf16 output ----------------
template<int V> struct VecSel;
template<> struct VecSel<2> { typedef float type __attribute__((ext_vector_type(2))); };
template<> struct VecSel<4> { typedef float type __attribute__((ext_vector_type(4))); };

template<int H>
__global__ __launch_bounds__(256)
void k_agg_split(const float* __restrict__ x, const float* __restrict__ dis,
                 const int* __restrict__ off, const int* __restrict__ csr,
                 const float* __restrict__ csrd,
                 unsigned short* __restrict__ hi, unsigned short* __restrict__ lo) {
  constexpr int V = H / 64;                  // floats per lane
  typedef typename VecSel<V>::type fv;
  const int lane = threadIdx.x & 63;
  const int node = blockIdx.x * 4 + (threadIdx.x >> 6);  // wave per node
  const float di = dis[node];
  const fv* xi = (const fv*)(x + (size_t)node * H) + lane;
  fv a0 = di * (*xi);
  fv a1 = (fv)0.f, a2 = (fv)0.f, a3 = (fv)0.f;
  const int e0 = off[node], e1 = off[node + 1];
  int e = e0;
  for (; e + 4 <= e1; e += 4) {
    int s0 = csr[e], s1 = csr[e + 1], s2 = csr[e + 2], s3 = csr[e + 3];
    float d0 = csrd[e], d1 = csrd[e + 1], d2 = csrd[e + 2], d3 = csrd[e + 3];
    fv v0 = *((const fv*)(x + (size_t)s0 * H) + lane);
    fv v1 = *((const fv*)(x + (size_t)s1 * H) + lane);
    fv v2 = *((const fv*)(x + (size_t)s2 * H) + lane);
    fv v3 = *((const fv*)(x + (size_t)s3 * H) + lane);
    a0 += d0 * v0; a1 += d1 * v1; a2 += d2 * v2; a3 += d3 * v3;
  }
  for (; e < e1; ++e) {
    int s0 = csr[e];
    float d0 = csrd[e];
    a0 += d0 * (*((const fv*)(x + (size_t)s0 * H) + lane));
  }
  fv r = di * ((a0 + a1) + (a2 + a3));
  unsigned short hb[V], lb[V];
  #pragma unroll
  for (int j = 0; j < V; ++j) {
    float v = r[j];
    __hip_bfloat16 h = __float2bfloat16(v);
    float hf = __bfloat162float(h);
    __hip_bfloat16 l16 = __float2bfloat16(v - hf);
    hb[j] = *(unsigned short*)&h;
    lb[j] = *(unsigned short*)&l16;
  }
  size_t base = (size_t)node * H + lane * V;
  if constexpr (V == 2) {
    *(ushort2*)&hi[base] = make_ushort2(hb[0], hb[1]);
    *(ushort2*)&lo[base] = make_ushort2(lb[0], lb[1]);
  } else {
    *(ushort4*)&hi[base] = make_ushort4(hb[0], hb[1], hb[2], hb[3]);
    *(ushort4*)&lo[base] = make_ushort4(lb[0], lb[1], lb[2], lb[3]);
  }
}

// ---------------- split-bf16 MFMA GEMM: C[N,256] = relu(A @ W + b) ----------------
// A given as Ah/Al [N][K] bf16; W given as Wt_hi/lo [256][K] bf16 (transposed).
// C = Ah*Wh + Ah*Wl + Al*Wh (AlWl dropped, ~2^-18 rel).
__device__ inline void gl_lds16(const void* g, void* l) {
  __builtin_amdgcn_global_load_lds((const __attribute__((address_space(1))) unsigned int*)g,
                                   (__attribute__((address_space(3))) unsigned int*)l,
                                   16, 0, 0);
}

template<int K>
__global__ __launch_bounds__(256)
void k_gemm_mfma(const unsigned short* __restrict__ Ah, const unsigned short* __restrict__ Al,
                 const unsigned short* __restrict__ Wh, const unsigned short* __restrict__ Wl,
                 const float* __restrict__ bias, float* __restrict__ C) {
  // BM=128, BN=128, BK=32; 4 waves in 2x2; per-wave 64x64 out.
  __shared__ unsigned short sAh[128 * 32];
  __shared__ unsigned short sAl[128 * 32];
  __shared__ unsigned short sBh[128 * 32];
  __shared__ unsigned short sBl[128 * 32];
  const int tid = threadIdx.x;
  const int lane = tid & 63;
  const int wid = tid >> 6;
  const int wr = wid >> 1, wc = wid & 1;
  const int row0 = blockIdx.x * 128;
  const int col0 = blockIdx.y * 128;
  const int cl = lane & 15;      // col-in-frag / row-in-frag
  const int sl = lane >> 4;      // k-slot 0..3

  f32x4 acc[4][4];
  #pragma unroll
  for (int i = 0; i < 4; ++i)
    #pragma unroll
    for (int j = 0; j < 4; ++j) acc[i][j] = (f32x4)0.f;

  for (int kt = 0; kt < K; kt += 32) {
    // ---- stage: linear LDS dest, inverse-swizzled global source ----
    #pragma unroll
    for (int q = 0; q < 2; ++q) {
      int c = (wid * 2 + q) * 64 + lane;    // chunk id 0..511
      int row = c >> 2, slot = c & 3;
      int ss = slot ^ (row & 3);            // involution swizzle
      int ga = row0 + row; if (ga > N_NODES - 1) ga = N_NODES - 1;
      size_t aoff = (size_t)ga * K + kt + ss * 8;
      unsigned short* ldst = (unsigned short*)sAh + (size_t)(wid * 2 + q) * 512;
      gl_lds16(Ah + aoff, ldst);
      unsigned short* ldst2 = (unsigned short*)sAl + (size_t)(wid * 2 + q) * 512;
      gl_lds16(Al + aoff, ldst2);
      size_t boff = (size_t)(col0 + row) * K + kt + ss * 8;
      unsigned short* ldst3 = (unsigned short*)sBh + (size_t)(wid * 2 + q) * 512;
      gl_lds16(Wh + boff, ldst3);
      unsigned short* ldst4 = (unsigned short*)sBl + (size_t)(wid * 2 + q) * 512;
      gl_lds16(Wl + boff, ldst4);
    }
    __syncthreads();   // vmcnt(0) drained by compiler before barrier

    // ---- fragments (swizzled read) ----
    bf16x8 fah[4], fal[4], fbh[4], fbl[4];
    #pragma unroll
    for (int f = 0; f < 4; ++f) {
      int ra = wr * 64 + f * 16 + cl;
      int oa = ra * 32 + ((sl ^ (ra & 3)) << 3);
      fah[f] = *(const bf16x8*)&sAh[oa];
      fal[f] = *(const bf16x8*)&sAl[oa];
      int rb = wc * 64 + f * 16 + cl;
      int ob = rb * 32 + ((sl ^ (rb & 3)) << 3);
      fbh[f] = *(const bf16x8*)&sBh[ob];
      fbl[f] = *(const bf16x8*)&sBl[ob];
    }
    #pragma unroll
    for (int i = 0; i < 4; ++i)
      #pragma unroll
      for (int j = 0; j < 4; ++j) {
        acc[i][j] = __builtin_amdgcn_mfma_f32_16x16x32_bf16(fah[i], fbh[j], acc[i][j], 0, 0, 0);
        acc[i][j] = __builtin_amdgcn_mfma_f32_16x16x32_bf16(fah[i], fbl[j], acc[i][j], 0, 0, 0);
        acc[i][j] = __builtin_amdgcn_mfma_f32_16x16x32_bf16(fal[i], fbh[j], acc[i][j], 0, 0, 0);
      }
    __syncthreads();
  }

  // ---- epilogue: bias + relu, f32 store ----
  #pragma unroll
  for (int j = 0; j < 4; ++j) {
    int gn = col0 + wc * 64 + j * 16 + cl;
    float bn = bias[gn];
    #pragma unroll
    for (int i = 0; i < 4; ++i) {
      f32x4 v = acc[i][j];
      #pragma unroll
      for (int r = 0; r < 4; ++r) {
        int gm = row0 + wr * 64 + i * 16 + sl * 4 + r;
        if (gm < N_NODES) C[(size_t)gm * HID + gn] = fmaxf(v[r] + bn, 0.f);
      }
    }
  }
}

// ---------------- pooling (mean + max per graph) ----------------
__device__ inline int lower_bound_i(const int* a, int n, int v) {
  int lo = 0, hi = n;
  while (lo < hi) { int m = (lo + hi) >> 1; if (a[m] < v) lo = m + 1; else hi = m; }
  return lo;
}

__global__ __launch_bounds__(256)
void k_pool(const float* __restrict__ x, const int* __restrict__ batch,
            float* __restrict__ g) {
  const int gi = blockIdx.x, t = threadIdx.x;
  const int start = lower_bound_i(batch, N_NODES, gi);
  const int end   = lower_bound_i(batch, N_NODES, gi + 1);
  float sum = 0.f, mx = 0.f;
  #pragma unroll 4
  for (int n = start; n < end; ++n) {
    float v = x[(size_t)n * HID + t];
    sum += v; mx = fmaxf(mx, v);
  }
  int cnt = end - start;
  g[gi * 512 + t] = sum / (float)(cnt > 0 ? cnt : 1);
  g[gi * 512 + 256 + t] = mx;
}

// ---------------- classifier head ----------------
__global__ __launch_bounds__(256)
void k_cls(const float* __restrict__ g, const float* __restrict__ Wc1,
           const float* __restrict__ bc1, const float* __restrict__ Wc2,
           const float* __restrict__ bc2, float* __restrict__ out) {
  const int gi = blockIdx.x, t = threadIdx.x;
  __shared__ float sg[512];
  __shared__ float sh[256];
  sg[t] = g[gi * 512 + t];
  sg[256 + t] = g[gi * 512 + 256 + t];
  __syncthreads();
  float a = bc1[t];
  #pragma unroll 8
  for (int k = 0; k < 512; ++k) a = fmaf(sg[k], Wc1[k * HID + t], a);
  sh[t] = fmaxf(a, 0.f);
  __syncthreads();
  if (t < 2) {
    float o = bc2[t];
    for (int k = 0; k < 256; ++k) o = fmaf(sh[k], Wc2[k * 2 + t], o);
    out[gi * 2 + t] = o;
  }
}

// ---------------- launch ----------------
extern "C" void kernel_launch(void* const* d_in, const int* in_sizes, int n_in,
                              void* d_out, int out_size, void* d_ws, size_t ws_size,
                              hipStream_t stream) {
  const int*   x_ids = (const int*)d_in[0];
  const int*   ei    = (const int*)d_in[1];
  const int*   batch = (const int*)d_in[2];
  const float* emb   = (const float*)d_in[3];
  const float* W0 = (const float*)d_in[4];  const float* b0 = (const float*)d_in[5];
  const float* W1 = (const float*)d_in[6];  const float* b1 = (const float*)d_in[7];
  const float* W2 = (const float*)d_in[8];  const float* b2 = (const float*)d_in[9];
  const float* W3 = (const float*)d_in[10]; const float* b3 = (const float*)d_in[11];
  const float* Wc1 = (const float*)d_in[12]; const float* bc1 = (const float*)d_in[13];
  const float* Wc2 = (const float*)d_in[14]; const float* bc2 = (const float*)d_in[15];
  float* out = (float*)d_out;
  const int* src = ei;
  const int* dst = ei + N_EDGES;

  char* ws = (char*)d_ws;
  size_t o = 0;
  auto alloc = [&](size_t bytes) -> char* {
    char* p = ws + o; o += (bytes + 255) & ~(size_t)255; return p;
  };
  float*          y    = (float*)alloc((size_t)N_NODES * HID * 4);     // f32 activations (also x0[N][128])
  unsigned short* Ahb  = (unsigned short*)alloc((size_t)N_NODES * HID * 2);
  unsigned short* Alb  = (unsigned short*)alloc((size_t)N_NODES * HID * 2);
  float* dis   = (float*)alloc((size_t)N_NODES * 4);
  int*   indeg = (int*)  alloc((size_t)N_NODES * 4);
  int*   off   = (int*)  alloc((size_t)(N_NODES + 1) * 4);
  int*   cur   = (int*)  alloc((size_t)(N_NODES + 1) * 4);
  int*   bsum  = (int*)  alloc((size_t)(NB_SCAN + 1) * 4);
  int*   csr   = (int*)  alloc((size_t)N_EDGES * 4);
  float* csrd  = (float*)alloc((size_t)N_EDGES * 4);
  unsigned short* wbuf = (unsigned short*)alloc((size_t)458752 * 2);
  float* gf    = (float*)alloc((size_t)N_GRAPHS * 512 * 4);
  (void)ws_size; (void)in_sizes; (void)n_in; (void)out_size;

  unsigned short* wt0h = wbuf;            unsigned short* wt0l = wbuf + 32768;
  unsigned short* wt1h = wbuf + 65536;    unsigned short* wt1l = wbuf + 131072;
  unsigned short* wt2h = wbuf + 196608;   unsigned short* wt2l = wbuf + 262144;
  unsigned short* wt3h = wbuf + 327680;   unsigned short* wt3l = wbuf + 393216;

  hipMemsetAsync(indeg, 0, (size_t)N_NODES * 4, stream);
  k_indeg<<<N_EDGES / 256, 256, 0, stream>>>(dst, indeg);
  k_dis<<<(N_NODES + 255) / 256, 256, 0, stream>>>(indeg, dis);
  k_scan1<<<NB_SCAN, 1024, 0, stream>>>(indeg, off, bsum);
  k_scan2<<<1, 64, 0, stream>>>(bsum);
  k_scan3<<<NB_SCAN, 1024, 0, stream>>>(off, cur, bsum);
  k_fill<<<N_EDGES / 256, 256, 0, stream>>>(src, dst, dis, cur, csr, csrd);
  k_embed<<<(N_NODES * 32) / 256, 256, 0, stream>>>(x_ids, emb, y);

  k_wsplit<<<128, 256, 0, stream>>>(W0, wt0h, wt0l, 128);
  k_wsplit<<<256, 256, 0, stream>>>(W1, wt1h, wt1l, 256);
  k_wsplit<<<256, 256, 0, stream>>>(W2, wt2h, wt2l, 256);
  k_wsplit<<<256, 256, 0, stream>>>(W3, wt3h, wt3l, 256);

  dim3 ggrid((N_NODES + 127) / 128, 2);
  // layer 0 (K = 128)
  k_agg_split<128><<<N_NODES / 4, 256, 0, stream>>>(y, dis, off, csr, csrd, Ahb, Alb);
  k_gemm_mfma<128><<<ggrid, 256, 0, stream>>>(Ahb, Alb, wt0h, wt0l, b0, y);
  // layers 1..3 (K = 256)
  k_agg_split<256><<<N_NODES / 4, 256, 0, stream>>>(y, dis, off, csr, csrd, Ahb, Alb);
  k_gemm_mfma<256><<<ggrid, 256, 0, stream>>>(Ahb, Alb, wt1h, wt1l, b1, y);
  k_agg_split<256><<<N_NODES / 4, 256, 0, stream>>>(y, dis, off, csr, csrd, Ahb, Alb);
  k_gemm_mfma<256><<<ggrid, 256, 0, stream>>>(Ahb, Alb, wt2h, wt2l, b2, y);
  k_agg_split<256><<<N_NODES / 4, 256, 0, stream>>>(y, dis, off, csr, csrd, Ahb, Alb);
  k_gemm_mfma<256><<<ggrid, 256, 0, stream>>>(Ahb, Alb, wt3h, wt3l, b3, y);

  k_pool<<<N_GRAPHS, 256, 0, stream>>>(y, batch, gf);
  k_cls<<<N_GRAPHS, 256, 0, stream>>>(gf, Wc1, bc1, Wc2, bc2, out);
}

// Round 5
// 1131.843 us; speedup vs baseline: 1.8141x; 1.3999x over previous
//
#include <hip/hip_runtime.h>
#include <hip/hip_bf16.h>
#include <cstdint>
#include <cstddef>

#define N_NODES 100000
#define N_EDGES 1600000
#define EMBD 128
#define HID 256
#define N_GRAPHS 128
#define VOCAB 1000
#define NB_SCAN 98   // ceil(N_NODES/1024)

typedef short bf16x8 __attribute__((ext_vector_type(8)));
typedef float f32x4 __attribute__((ext_vector_type(4)));
typedef float f32x2 __attribute__((ext_vector_type(2)));

__device__ inline unsigned short rne_bf16(float f) {
  unsigned u = __float_as_uint(f);
  return (unsigned short)((u + 0x7FFFu + ((u >> 16) & 1u)) >> 16);
}
__device__ inline float bf16_to_f32(unsigned short h) {
  return __uint_as_float(((unsigned)h) << 16);
}
__device__ inline void split_hl(float v, unsigned short& h, unsigned short& l) {
  h = rne_bf16(v);
  float hf = __uint_as_float(((unsigned)h) << 16);
  l = rne_bf16(v - hf);
}
__device__ inline f32x4 cvt4(uint2 v) {
  f32x4 r;
  r[0] = __uint_as_float(v.x << 16);
  r[1] = __uint_as_float(v.x & 0xFFFF0000u);
  r[2] = __uint_as_float(v.y << 16);
  r[3] = __uint_as_float(v.y & 0xFFFF0000u);
  return r;
}
__device__ inline f32x2 cvt2(unsigned v) {
  f32x2 r;
  r[0] = __uint_as_float(v << 16);
  r[1] = __uint_as_float(v & 0xFFFF0000u);
  return r;
}

// ---------------- CSR build ----------------
__global__ void k_indeg(const int* __restrict__ dst, int* __restrict__ indeg) {
  int e = blockIdx.x * 256 + threadIdx.x;
  if (e < N_EDGES) atomicAdd(&indeg[dst[e]], 1);
}

__global__ void k_dis(const int* __restrict__ indeg, float* __restrict__ dis) {
  int i = blockIdx.x * 256 + threadIdx.x;
  if (i < N_NODES) dis[i] = rsqrtf((float)(indeg[i] + 1));
}

__global__ __launch_bounds__(1024)
void k_scan1(const int* __restrict__ indeg, int* __restrict__ off, int* __restrict__ bsum) {
  __shared__ int s[1024];
  const int tid = threadIdx.x;
  int i = blockIdx.x * 1024 + tid;
  int v = (i < N_NODES) ? indeg[i] : 0;
  s[tid] = v; __syncthreads();
  #pragma unroll
  for (int ofs = 1; ofs < 1024; ofs <<= 1) {
    int t2 = (tid >= ofs) ? s[tid - ofs] : 0;
    __syncthreads();
    s[tid] += t2;
    __syncthreads();
  }
  if (i < N_NODES) off[i] = s[tid] - v;      // exclusive within block
  if (tid == 1023) bsum[blockIdx.x] = s[1023];
}

__global__ void k_scan2(int* __restrict__ bsum) {
  if (threadIdx.x == 0) {
    int a = 0;
    for (int i = 0; i < NB_SCAN; ++i) { int t = bsum[i]; bsum[i] = a; a += t; }
    bsum[NB_SCAN] = a;
  }
}

__global__ __launch_bounds__(1024)
void k_scan3(int* __restrict__ off, int* __restrict__ cur, const int* __restrict__ bsum) {
  int i = blockIdx.x * 1024 + threadIdx.x;
  if (i < N_NODES) { int v = off[i] + bsum[blockIdx.x]; off[i] = v; cur[i] = v; }
  if (i == 0) off[N_NODES] = bsum[NB_SCAN];
}

__global__ void k_fill(const int* __restrict__ src, const int* __restrict__ dst,
                       const int* __restrict__ ids, const float* __restrict__ dis,
                       int* __restrict__ cursor, int2* __restrict__ csre,
                       int2* __restrict__ csre0) {
  int e = blockIdx.x * 256 + threadIdx.x;
  if (e < N_EDGES) {
    int s = src[e];
    float ds = dis[s];
    int p = atomicAdd(&cursor[dst[e]], 1);
    csre[p]  = make_int2(s, __float_as_int(ds));
    csre0[p] = make_int2(ids[s], __float_as_int(ds));
  }
}

// ---------------- emb -> bf16 (256 KB, L2-resident) ----------------
__global__ void k_emb16(const float* __restrict__ emb, unsigned short* __restrict__ emb16) {
  int i = blockIdx.x * 256 + threadIdx.x;   // VOCAB*EMBD = 128000
  if (i < VOCAB * EMBD) emb16[i] = rne_bf16(emb[i]);
}

// ---------------- W split/transpose prep ----------------
__global__ void k_wsplit(const float* __restrict__ W, unsigned short* __restrict__ th,
                         unsigned short* __restrict__ tl, int K) {
  int i = blockIdx.x * 256 + threadIdx.x;    // over K*256
  int k = i >> 8, n = i & 255;
  float v = W[i];
  unsigned short h, l;
  split_hl(v, h, l);
  th[n * K + k] = h;
  tl[n * K + k] = l;
}

// ---------------- layer-0 aggregation: gather emb16 rows via ids (L2-hit) ----------------
__global__ __launch_bounds__(256)
void k_agg0(const unsigned short* __restrict__ emb16, const int* __restrict__ ids,
            const float* __restrict__ dis, const int* __restrict__ off,
            const int2* __restrict__ csre0,
            unsigned short* __restrict__ hi, unsigned short* __restrict__ lo) {
  const int lane = threadIdx.x & 63;
  const int node = blockIdx.x * 4 + (threadIdx.x >> 6);  // wave per node
  const float di = dis[node];
  unsigned sv = *((const unsigned*)(emb16 + (size_t)ids[node] * EMBD) + lane);
  f32x2 a0 = di * cvt2(sv);
  f32x2 a1 = (f32x2)0.f, a2 = (f32x2)0.f, a3 = (f32x2)0.f;
  const int e0 = off[node], e1 = off[node + 1];
  int e = e0;
  for (; e + 4 <= e1; e += 4) {
    int2 c0 = csre0[e], c1 = csre0[e + 1], c2 = csre0[e + 2], c3 = csre0[e + 3];
    unsigned v0 = *((const unsigned*)(emb16 + (size_t)c0.x * EMBD) + lane);
    unsigned v1 = *((const unsigned*)(emb16 + (size_t)c1.x * EMBD) + lane);
    unsigned v2 = *((const unsigned*)(emb16 + (size_t)c2.x * EMBD) + lane);
    unsigned v3 = *((const unsigned*)(emb16 + (size_t)c3.x * EMBD) + lane);
    a0 += __int_as_float(c0.y) * cvt2(v0);
    a1 += __int_as_float(c1.y) * cvt2(v1);
    a2 += __int_as_float(c2.y) * cvt2(v2);
    a3 += __int_as_float(c3.y) * cvt2(v3);
  }
  for (; e < e1; ++e) {
    int2 c0 = csre0[e];
    unsigned v0 = *((const unsigned*)(emb16 + (size_t)c0.x * EMBD) + lane);
    a0 += __int_as_float(c0.y) * cvt2(v0);
  }
  f32x2 r = di * ((a0 + a1) + (a2 + a3));
  unsigned short hb[2], lb[2];
  split_hl(r[0], hb[0], lb[0]);
  split_hl(r[1], hb[1], lb[1]);
  size_t base = (size_t)node * EMBD + lane * 2;
  *(ushort2*)&hi[base] = make_ushort2(hb[0], hb[1]);
  *(ushort2*)&lo[base] = make_ushort2(lb[0], lb[1]);
}

// ---------------- layers 1-3 aggregation: gather bf16 activation rows ----------------
__global__ __launch_bounds__(256)
void k_agg16(const unsigned short* __restrict__ y16, const float* __restrict__ dis,
             const int* __restrict__ off, const int2* __restrict__ csre,
             unsigned short* __restrict__ hi, unsigned short* __restrict__ lo) {
  const int lane = threadIdx.x & 63;
  const int node = blockIdx.x * 4 + (threadIdx.x >> 6);  // wave per node
  const float di = dis[node];
  uint2 sv = *((const uint2*)(y16 + (size_t)node * HID) + lane);
  f32x4 a0 = di * cvt4(sv);
  f32x4 a1 = (f32x4)0.f, a2 = (f32x4)0.f, a3 = (f32x4)0.f;
  const int e0 = off[node], e1 = off[node + 1];
  int e = e0;
  for (; e + 4 <= e1; e += 4) {
    int2 c0 = csre[e], c1 = csre[e + 1], c2 = csre[e + 2], c3 = csre[e + 3];
    uint2 v0 = *((const uint2*)(y16 + (size_t)c0.x * HID) + lane);
    uint2 v1 = *((const uint2*)(y16 + (size_t)c1.x * HID) + lane);
    uint2 v2 = *((const uint2*)(y16 + (size_t)c2.x * HID) + lane);
    uint2 v3 = *((const uint2*)(y16 + (size_t)c3.x * HID) + lane);
    a0 += __int_as_float(c0.y) * cvt4(v0);
    a1 += __int_as_float(c1.y) * cvt4(v1);
    a2 += __int_as_float(c2.y) * cvt4(v2);
    a3 += __int_as_float(c3.y) * cvt4(v3);
  }
  for (; e < e1; ++e) {
    int2 c0 = csre[e];
    uint2 v0 = *((const uint2*)(y16 + (size_t)c0.x * HID) + lane);
    a0 += __int_as_float(c0.y) * cvt4(v0);
  }
  f32x4 r = di * ((a0 + a1) + (a2 + a3));
  unsigned short hb[4], lb[4];
  #pragma unroll
  for (int j = 0; j < 4; ++j) split_hl(r[j], hb[j], lb[j]);
  size_t base = (size_t)node * HID + lane * 4;
  *(ushort4*)&hi[base] = make_ushort4(hb[0], hb[1], hb[2], hb[3]);
  *(ushort4*)&lo[base] = make_ushort4(lb[0], lb[1], lb[2], lb[3]);
}

// ---------------- split-bf16 MFMA GEMM: y16[N,256] = bf16(relu(A @ W + b)) ----------------
__device__ inline void gl_lds16(const void* g, void* l) {
  __builtin_amdgcn_global_load_lds((const __attribute__((address_space(1))) unsigned int*)g,
                                   (__attribute__((address_space(3))) unsigned int*)l,
                                   16, 0, 0);
}

template<int K>
__global__ __launch_bounds__(256)
void k_gemm_mfma(const unsigned short* __restrict__ Ah, const unsigned short* __restrict__ Al,
                 const unsigned short* __restrict__ Wh, const unsigned short* __restrict__ Wl,
                 const float* __restrict__ bias, unsigned short* __restrict__ C16) {
  // BM=128, BN=128, BK=32; 4 waves in 2x2; per-wave 64x64 out.
  __shared__ unsigned short sAh[128 * 32];
  __shared__ unsigned short sAl[128 * 32];
  __shared__ unsigned short sBh[128 * 32];
  __shared__ unsigned short sBl[128 * 32];
  const int tid = threadIdx.x;
  const int lane = tid & 63;
  const int wid = tid >> 6;
  const int wr = wid >> 1, wc = wid & 1;
  const int row0 = blockIdx.x * 128;
  const int col0 = blockIdx.y * 128;
  const int cl = lane & 15;      // col-in-frag / row-in-frag
  const int sl = lane >> 4;      // k-slot 0..3

  f32x4 acc[4][4];
  #pragma unroll
  for (int i = 0; i < 4; ++i)
    #pragma unroll
    for (int j = 0; j < 4; ++j) acc[i][j] = (f32x4)0.f;

  for (int kt = 0; kt < K; kt += 32) {
    // ---- stage: linear LDS dest, inverse-swizzled global source ----
    #pragma unroll
    for (int q = 0; q < 2; ++q) {
      int c = (wid * 2 + q) * 64 + lane;    // chunk id 0..511
      int row = c >> 2, slot = c & 3;
      int ss = slot ^ (row & 3);            // involution swizzle
      int ga = row0 + row; if (ga > N_NODES - 1) ga = N_NODES - 1;
      size_t aoff = (size_t)ga * K + kt + ss * 8;
      gl_lds16(Ah + aoff, (unsigned short*)sAh + (size_t)(wid * 2 + q) * 512);
      gl_lds16(Al + aoff, (unsigned short*)sAl + (size_t)(wid * 2 + q) * 512);
      size_t boff = (size_t)(col0 + row) * K + kt + ss * 8;
      gl_lds16(Wh + boff, (unsigned short*)sBh + (size_t)(wid * 2 + q) * 512);
      gl_lds16(Wl + boff, (unsigned short*)sBl + (size_t)(wid * 2 + q) * 512);
    }
    __syncthreads();

    // ---- fragments (swizzled read) ----
    bf16x8 fah[4], fal[4], fbh[4], fbl[4];
    #pragma unroll
    for (int f = 0; f < 4; ++f) {
      int ra = wr * 64 + f * 16 + cl;
      int oa = ra * 32 + ((sl ^ (ra & 3)) << 3);
      fah[f] = *(const bf16x8*)&sAh[oa];
      fal[f] = *(const bf16x8*)&sAl[oa];
      int rb = wc * 64 + f * 16 + cl;
      int ob = rb * 32 + ((sl ^ (rb & 3)) << 3);
      fbh[f] = *(const bf16x8*)&sBh[ob];
      fbl[f] = *(const bf16x8*)&sBl[ob];
    }
    #pragma unroll
    for (int i = 0; i < 4; ++i)
      #pragma unroll
      for (int j = 0; j < 4; ++j) {
        acc[i][j] = __builtin_amdgcn_mfma_f32_16x16x32_bf16(fah[i], fbh[j], acc[i][j], 0, 0, 0);
        acc[i][j] = __builtin_amdgcn_mfma_f32_16x16x32_bf16(fah[i], fbl[j], acc[i][j], 0, 0, 0);
        acc[i][j] = __builtin_amdgcn_mfma_f32_16x16x32_bf16(fal[i], fbh[j], acc[i][j], 0, 0, 0);
      }
    __syncthreads();
  }

  // ---- epilogue: bias + relu, bf16 store ----
  #pragma unroll
  for (int j = 0; j < 4; ++j) {
    int gn = col0 + wc * 64 + j * 16 + cl;
    float bn = bias[gn];
    #pragma unroll
    for (int i = 0; i < 4; ++i) {
      f32x4 v = acc[i][j];
      #pragma unroll
      for (int r = 0; r < 4; ++r) {
        int gm = row0 + wr * 64 + i * 16 + sl * 4 + r;
        if (gm < N_NODES) C16[(size_t)gm * HID + gn] = rne_bf16(fmaxf(v[r] + bn, 0.f));
      }
    }
  }
}

// ---------------- pooling (mean + max per graph) from bf16 ----------------
__device__ inline int lower_bound_i(const int* a, int n, int v) {
  int lo = 0, hi = n;
  while (lo < hi) { int m = (lo + hi) >> 1; if (a[m] < v) lo = m + 1; else hi = m; }
  return lo;
}

__global__ __launch_bounds__(256)
void k_pool(const unsigned short* __restrict__ y16, const int* __restrict__ batch,
            float* __restrict__ g) {
  const int gi = blockIdx.x, t = threadIdx.x;
  const int start = lower_bound_i(batch, N_NODES, gi);
  const int end   = lower_bound_i(batch, N_NODES, gi + 1);
  float sum = 0.f, mx = 0.f;
  #pragma unroll 4
  for (int n = start; n < end; ++n) {
    float v = bf16_to_f32(y16[(size_t)n * HID + t]);
    sum += v; mx = fmaxf(mx, v);
  }
  int cnt = end - start;
  g[gi * 512 + t] = sum / (float)(cnt > 0 ? cnt : 1);
  g[gi * 512 + 256 + t] = mx;
}

// ---------------- classifier head ----------------
__global__ __launch_bounds__(256)
void k_cls(const float* __restrict__ g, const float* __restrict__ Wc1,
           const float* __restrict__ bc1, const float* __restrict__ Wc2,
           const float* __restrict__ bc2, float* __restrict__ out) {
  const int gi = blockIdx.x, t = threadIdx.x;
  __shared__ float sg[512];
  __shared__ float sh[256];
  sg[t] = g[gi * 512 + t];
  sg[256 + t] = g[gi * 512 + 256 + t];
  __syncthreads();
  float a = bc1[t];
  #pragma unroll 8
  for (int k = 0; k < 512; ++k) a = fmaf(sg[k], Wc1[k * HID + t], a);
  sh[t] = fmaxf(a, 0.f);
  __syncthreads();
  if (t < 2) {
    float o = bc2[t];
    for (int k = 0; k < 256; ++k) o = fmaf(sh[k], Wc2[k * 2 + t], o);
    out[gi * 2 + t] = o;
  }
}

// ---------------- launch ----------------
extern "C" void kernel_launch(void* const* d_in, const int* in_sizes, int n_in,
                              void* d_out, int out_size, void* d_ws, size_t ws_size,
                              hipStream_t stream) {
  const int*   x_ids = (const int*)d_in[0];
  const int*   ei    = (const int*)d_in[1];
  const int*   batch = (const int*)d_in[2];
  const float* emb   = (const float*)d_in[3];
  const float* W0 = (const float*)d_in[4];  const float* b0 = (const float*)d_in[5];
  const float* W1 = (const float*)d_in[6];  const float* b1 = (const float*)d_in[7];
  const float* W2 = (const float*)d_in[8];  const float* b2 = (const float*)d_in[9];
  const float* W3 = (const float*)d_in[10]; const float* b3 = (const float*)d_in[11];
  const float* Wc1 = (const float*)d_in[12]; const float* bc1 = (const float*)d_in[13];
  const float* Wc2 = (const float*)d_in[14]; const float* bc2 = (const float*)d_in[15];
  float* out = (float*)d_out;
  const int* src = ei;
  const int* dst = ei + N_EDGES;

  char* ws = (char*)d_ws;
  size_t o = 0;
  auto alloc = [&](size_t bytes) -> char* {
    char* p = ws + o; o += (bytes + 255) & ~(size_t)255; return p;
  };
  unsigned short* y16 = (unsigned short*)alloc((size_t)N_NODES * HID * 2);
  unsigned short* Ahb = (unsigned short*)alloc((size_t)N_NODES * HID * 2);
  unsigned short* Alb = (unsigned short*)alloc((size_t)N_NODES * HID * 2);
  float* dis   = (float*)alloc((size_t)N_NODES * 4);
  int*   indeg = (int*)  alloc((size_t)N_NODES * 4);
  int*   off   = (int*)  alloc((size_t)(N_NODES + 1) * 4);
  int*   cur   = (int*)  alloc((size_t)(N_NODES + 1) * 4);
  int*   bsum  = (int*)  alloc((size_t)(NB_SCAN + 1) * 4);
  int2*  csre  = (int2*) alloc((size_t)N_EDGES * 8);
  int2*  csre0 = (int2*) alloc((size_t)N_EDGES * 8);
  unsigned short* emb16 = (unsigned short*)alloc((size_t)VOCAB * EMBD * 2);
  unsigned short* wbuf  = (unsigned short*)alloc((size_t)458752 * 2);
  float* gf    = (float*)alloc((size_t)N_GRAPHS * 512 * 4);
  (void)ws_size; (void)in_sizes; (void)n_in; (void)out_size;

  unsigned short* wt0h = wbuf;            unsigned short* wt0l = wbuf + 32768;
  unsigned short* wt1h = wbuf + 65536;    unsigned short* wt1l = wbuf + 131072;
  unsigned short* wt2h = wbuf + 196608;   unsigned short* wt2l = wbuf + 262144;
  unsigned short* wt3h = wbuf + 327680;   unsigned short* wt3l = wbuf + 393216;

  hipMemsetAsync(indeg, 0, (size_t)N_NODES * 4, stream);
  k_indeg<<<N_EDGES / 256, 256, 0, stream>>>(dst, indeg);
  k_dis<<<(N_NODES + 255) / 256, 256, 0, stream>>>(indeg, dis);
  k_scan1<<<NB_SCAN, 1024, 0, stream>>>(indeg, off, bsum);
  k_scan2<<<1, 64, 0, stream>>>(bsum);
  k_scan3<<<NB_SCAN, 1024, 0, stream>>>(off, cur, bsum);
  k_fill<<<N_EDGES / 256, 256, 0, stream>>>(src, dst, x_ids, dis, cur, csre, csre0);
  k_emb16<<<(VOCAB * EMBD + 255) / 256, 256, 0, stream>>>(emb, emb16);

  k_wsplit<<<128, 256, 0, stream>>>(W0, wt0h, wt0l, 128);
  k_wsplit<<<256, 256, 0, stream>>>(W1, wt1h, wt1l, 256);
  k_wsplit<<<256, 256, 0, stream>>>(W2, wt2h, wt2l, 256);
  k_wsplit<<<256, 256, 0, stream>>>(W3, wt3h, wt3l, 256);

  dim3 ggrid((N_NODES + 127) / 128, 2);
  // layer 0 (K = 128): gather directly from L2-resident emb16
  k_agg0<<<N_NODES / 4, 256, 0, stream>>>(emb16, x_ids, dis, off, csre0, Ahb, Alb);
  k_gemm_mfma<128><<<ggrid, 256, 0, stream>>>(Ahb, Alb, wt0h, wt0l, b0, y16);
  // layers 1..3 (K = 256): gather bf16 activations
  k_agg16<<<N_NODES / 4, 256, 0, stream>>>(y16, dis, off, csre, Ahb, Alb);
  k_gemm_mfma<256><<<ggrid, 256, 0, stream>>>(Ahb, Alb, wt1h, wt1l, b1, y16);
  k_agg16<<<N_NODES / 4, 256, 0, stream>>>(y16, dis, off, csre, Ahb, Alb);
  k_gemm_mfma<256><<<ggrid, 256, 0, stream>>>(Ahb, Alb, wt2h, wt2l, b2, y16);
  k_agg16<<<N_NODES / 4, 256, 0, stream>>>(y16, dis, off, csre, Ahb, Alb);
  k_gemm_mfma<256><<<ggrid, 256, 0, stream>>>(Ahb, Alb, wt3h, wt3l, b3, y16);

  k_pool<<<N_GRAPHS, 256, 0, stream>>>(y16, batch, gf);
  k_cls<<<N_GRAPHS, 256, 0, stream>>>(gf, Wc1, bc1, Wc2, bc2, out);
}

// Round 7
// 978.796 us; speedup vs baseline: 2.0978x; 1.1564x over previous
//
#include <hip/hip_runtime.h>
#include <hip/hip_bf16.h>
#include <cstdint>
#include <cstddef>

#define N_NODES 100000
#define N_EDGES 1600000
#define EMBD 128
#define HID 256
#define N_GRAPHS 128
#define VOCAB 1000
#define NB_SCAN 98   // ceil(N_NODES/1024)

typedef short bf16x8 __attribute__((ext_vector_type(8)));
typedef float f32x4 __attribute__((ext_vector_type(4)));
typedef float f32x2 __attribute__((ext_vector_type(2)));

__device__ inline unsigned short rne_bf16(float f) {
  unsigned u = __float_as_uint(f);
  return (unsigned short)((u + 0x7FFFu + ((u >> 16) & 1u)) >> 16);
}
__device__ inline float bf16_to_f32(unsigned short h) {
  return __uint_as_float(((unsigned)h) << 16);
}
__device__ inline void split_hl(float v, unsigned short& h, unsigned short& l) {
  h = rne_bf16(v);
  float hf = __uint_as_float(((unsigned)h) << 16);
  l = rne_bf16(v - hf);
}
__device__ inline f32x4 cvt4(uint2 v) {
  f32x4 r;
  r[0] = __uint_as_float(v.x << 16);
  r[1] = __uint_as_float(v.x & 0xFFFF0000u);
  r[2] = __uint_as_float(v.y << 16);
  r[3] = __uint_as_float(v.y & 0xFFFF0000u);
  return r;
}
__device__ inline f32x2 cvt2(unsigned v) {
  f32x2 r;
  r[0] = __uint_as_float(v << 16);
  r[1] = __uint_as_float(v & 0xFFFF0000u);
  return r;
}

// ---------------- CSR build ----------------
__global__ void k_indeg(const int* __restrict__ dst, int* __restrict__ indeg) {
  int e = blockIdx.x * 256 + threadIdx.x;
  if (e < N_EDGES) atomicAdd(&indeg[dst[e]], 1);
}

__global__ __launch_bounds__(1024)
void k_scan1(const int* __restrict__ indeg, int* __restrict__ off, int* __restrict__ bsum,
             float* __restrict__ dis) {
  __shared__ int s[1024];
  const int tid = threadIdx.x;
  int i = blockIdx.x * 1024 + tid;
  int v = (i < N_NODES) ? indeg[i] : 0;
  if (i < N_NODES) dis[i] = rsqrtf((float)(v + 1));   // fused degree-norm
  s[tid] = v; __syncthreads();
  #pragma unroll
  for (int ofs = 1; ofs < 1024; ofs <<= 1) {
    int t2 = (tid >= ofs) ? s[tid - ofs] : 0;
    __syncthreads();
    s[tid] += t2;
    __syncthreads();
  }
  if (i < N_NODES) off[i] = s[tid] - v;      // exclusive within block
  if (tid == 1023) bsum[blockIdx.x] = s[1023];
}

__global__ void k_scan2(int* __restrict__ bsum) {
  if (threadIdx.x == 0) {
    int a = 0;
    for (int i = 0; i < NB_SCAN; ++i) { int t = bsum[i]; bsum[i] = a; a += t; }
    bsum[NB_SCAN] = a;
  }
}

__global__ __launch_bounds__(1024)
void k_scan3(int* __restrict__ off, int* __restrict__ cur, const int* __restrict__ bsum) {
  int i = blockIdx.x * 1024 + threadIdx.x;
  if (i < N_NODES) { int v = off[i] + bsum[blockIdx.x]; off[i] = v; cur[i] = v; }
  if (i == 0) off[N_NODES] = bsum[NB_SCAN];
}

__global__ void k_fill(const int* __restrict__ src, const int* __restrict__ dst,
                       const int* __restrict__ ids, const float* __restrict__ dis,
                       int* __restrict__ cursor, int2* __restrict__ csre,
                       int2* __restrict__ csre0) {
  int e = blockIdx.x * 256 + threadIdx.x;
  if (e < N_EDGES) {
    int s = src[e];
    float ds = dis[s];
    int p = atomicAdd(&cursor[dst[e]], 1);
    csre[p]  = make_int2(s, __float_as_int(ds));
    csre0[p] = make_int2(ids[s], __float_as_int(ds));
  }
}

// ---------------- fused prep: emb->bf16 + W transpose/split ----------------
// segments: [0,128000) emb16 ; [128000,160768) W0 ; [160768,357376) W1..W3
__global__ void k_prep(const float* __restrict__ emb, unsigned short* __restrict__ emb16,
                       const float* __restrict__ W0, unsigned short* __restrict__ w0h,
                       unsigned short* __restrict__ w0l,
                       const float* __restrict__ W1, unsigned short* __restrict__ w1h,
                       unsigned short* __restrict__ w1l,
                       const float* __restrict__ W2, unsigned short* __restrict__ w2h,
                       unsigned short* __restrict__ w2l,
                       const float* __restrict__ W3, unsigned short* __restrict__ w3h,
                       unsigned short* __restrict__ w3l) {
  int i = blockIdx.x * 256 + threadIdx.x;
  if (i < VOCAB * EMBD) { emb16[i] = rne_bf16(emb[i]); return; }
  i -= VOCAB * EMBD;
  unsigned short h, l;
  if (i < EMBD * HID) {               // W0: [128][256] -> [256][128] split
    int k = i >> 8, n = i & 255;
    split_hl(W0[i], h, l);
    w0h[n * EMBD + k] = h; w0l[n * EMBD + k] = l;
    return;
  }
  i -= EMBD * HID;
  if (i >= 3 * HID * HID) return;
  int w = i >> 16, j = i & 65535;     // W1..W3: [256][256] -> [256][256] split
  const float* Ws = (w == 0) ? W1 : (w == 1) ? W2 : W3;
  unsigned short* th = (w == 0) ? w1h : (w == 1) ? w2h : w3h;
  unsigned short* tl = (w == 0) ? w1l : (w == 1) ? w2l : w3l;
  int k = j >> 8, n = j & 255;
  split_hl(Ws[j], h, l);
  th[n * HID + k] = h; tl[n * HID + k] = l;
}

// ---------------- layer-0 aggregation: gather emb16 rows via ids (L2-hit) ----------------
__global__ __launch_bounds__(256)
void k_agg0(const unsigned short* __restrict__ emb16, const int* __restrict__ ids,
            const float* __restrict__ dis, const int* __restrict__ off,
            const int2* __restrict__ csre0, unsigned short* __restrict__ aggA) {
  const int lane = threadIdx.x & 63;
  const int node = blockIdx.x * 4 + (threadIdx.x >> 6);  // wave per node
  const float di = dis[node];
  unsigned sv = *((const unsigned*)(emb16 + (size_t)ids[node] * EMBD) + lane);
  f32x2 a0 = di * cvt2(sv);
  f32x2 a1 = (f32x2)0.f, a2 = (f32x2)0.f, a3 = (f32x2)0.f;
  const int e0 = off[node], e1 = off[node + 1];
  int e = e0;
  for (; e + 4 <= e1; e += 4) {
    int2 c0 = csre0[e], c1 = csre0[e + 1], c2 = csre0[e + 2], c3 = csre0[e + 3];
    unsigned v0 = *((const unsigned*)(emb16 + (size_t)c0.x * EMBD) + lane);
    unsigned v1 = *((const unsigned*)(emb16 + (size_t)c1.x * EMBD) + lane);
    unsigned v2 = *((const unsigned*)(emb16 + (size_t)c2.x * EMBD) + lane);
    unsigned v3 = *((const unsigned*)(emb16 + (size_t)c3.x * EMBD) + lane);
    a0 += __int_as_float(c0.y) * cvt2(v0);
    a1 += __int_as_float(c1.y) * cvt2(v1);
    a2 += __int_as_float(c2.y) * cvt2(v2);
    a3 += __int_as_float(c3.y) * cvt2(v3);
  }
  for (; e < e1; ++e) {
    int2 c0 = csre0[e];
    unsigned v0 = *((const unsigned*)(emb16 + (size_t)c0.x * EMBD) + lane);
    a0 += __int_as_float(c0.y) * cvt2(v0);
  }
  f32x2 r = di * ((a0 + a1) + (a2 + a3));
  size_t base = (size_t)node * EMBD + lane * 2;
  *(ushort2*)&aggA[base] = make_ushort2(rne_bf16(r[0]), rne_bf16(r[1]));
}

// ---------------- layers 1-3 aggregation: gather bf16 activation rows ----------------
__global__ __launch_bounds__(256)
void k_agg16(const unsigned short* __restrict__ y16, const float* __restrict__ dis,
             const int* __restrict__ off, const int2* __restrict__ csre,
             unsigned short* __restrict__ aggA) {
  const int lane = threadIdx.x & 63;
  const int node = blockIdx.x * 4 + (threadIdx.x >> 6);  // wave per node
  const float di = dis[node];
  uint2 sv = *((const uint2*)(y16 + (size_t)node * HID) + lane);
  f32x4 a0 = di * cvt4(sv);
  f32x4 a1 = (f32x4)0.f, a2 = (f32x4)0.f, a3 = (f32x4)0.f;
  const int e0 = off[node], e1 = off[node + 1];
  int e = e0;
  for (; e + 4 <= e1; e += 4) {
    int2 c0 = csre[e], c1 = csre[e + 1], c2 = csre[e + 2], c3 = csre[e + 3];
    uint2 v0 = *((const uint2*)(y16 + (size_t)c0.x * HID) + lane);
    uint2 v1 = *((const uint2*)(y16 + (size_t)c1.x * HID) + lane);
    uint2 v2 = *((const uint2*)(y16 + (size_t)c2.x * HID) + lane);
    uint2 v3 = *((const uint2*)(y16 + (size_t)c3.x * HID) + lane);
    a0 += __int_as_float(c0.y) * cvt4(v0);
    a1 += __int_as_float(c1.y) * cvt4(v1);
    a2 += __int_as_float(c2.y) * cvt4(v2);
    a3 += __int_as_float(c3.y) * cvt4(v3);
  }
  for (; e < e1; ++e) {
    int2 c0 = csre[e];
    uint2 v0 = *((const uint2*)(y16 + (size_t)c0.x * HID) + lane);
    a0 += __int_as_float(c0.y) * cvt4(v0);
  }
  f32x4 r = di * ((a0 + a1) + (a2 + a3));
  size_t base = (size_t)node * HID + lane * 4;
  *(ushort4*)&aggA[base] = make_ushort4(rne_bf16(r[0]), rne_bf16(r[1]),
                                        rne_bf16(r[2]), rne_bf16(r[3]));
}

// ---------------- MFMA GEMM: y16 = bf16(relu(A @ (Wh+Wl) + b)) ----------------
// A: [N][K] bf16 (single); W: [256][K] bf16 hi/lo (transposed). 2 MFMA products.
__device__ inline void gl_lds16(const void* g, void* l) {
  __builtin_amdgcn_global_load_lds((const __attribute__((address_space(1))) unsigned int*)g,
                                   (__attribute__((address_space(3))) unsigned int*)l,
                                   16, 0, 0);
}

template<int K>
__global__ __launch_bounds__(256)
void k_gemm_mfma(const unsigned short* __restrict__ Ah,
                 const unsigned short* __restrict__ Wh, const unsigned short* __restrict__ Wl,
                 const float* __restrict__ bias, unsigned short* __restrict__ C16) {
  // BM=128, BN=128, BK=32; 4 waves in 2x2; per-wave 64x64 out.
  __shared__ unsigned short sA[128 * 32];
  __shared__ unsigned short sBh[128 * 32];
  __shared__ unsigned short sBl[128 * 32];
  const int tid = threadIdx.x;
  const int lane = tid & 63;
  const int wid = tid >> 6;
  const int wr = wid >> 1, wc = wid & 1;
  const int row0 = blockIdx.x * 128;
  const int col0 = blockIdx.y * 128;
  const int cl = lane & 15;      // col-in-frag / row-in-frag
  const int sl = lane >> 4;      // k-slot 0..3

  f32x4 acc[4][4];
  #pragma unroll
  for (int i = 0; i < 4; ++i)
    #pragma unroll
    for (int j = 0; j < 4; ++j) acc[i][j] = (f32x4)0.f;

  for (int kt = 0; kt < K; kt += 32) {
    // ---- stage: linear LDS dest, inverse-swizzled global source ----
    #pragma unroll
    for (int q = 0; q < 2; ++q) {
      int c = (wid * 2 + q) * 64 + lane;    // chunk id 0..511
      int row = c >> 2, slot = c & 3;
      int ss = slot ^ (row & 3);            // involution swizzle
      int ga = row0 + row; if (ga > N_NODES - 1) ga = N_NODES - 1;
      size_t aoff = (size_t)ga * K + kt + ss * 8;
      gl_lds16(Ah + aoff, (unsigned short*)sA + (size_t)(wid * 2 + q) * 512);
      size_t boff = (size_t)(col0 + row) * K + kt + ss * 8;
      gl_lds16(Wh + boff, (unsigned short*)sBh + (size_t)(wid * 2 + q) * 512);
      gl_lds16(Wl + boff, (unsigned short*)sBl + (size_t)(wid * 2 + q) * 512);
    }
    __syncthreads();

    // ---- fragments (swizzled read) ----
    bf16x8 fa[4], fbh[4], fbl[4];
    #pragma unroll
    for (int f = 0; f < 4; ++f) {
      int ra = wr * 64 + f * 16 + cl;
      int oa = ra * 32 + ((sl ^ (ra & 3)) << 3);
      fa[f] = *(const bf16x8*)&sA[oa];
      int rb = wc * 64 + f * 16 + cl;
      int ob = rb * 32 + ((sl ^ (rb & 3)) << 3);
      fbh[f] = *(const bf16x8*)&sBh[ob];
      fbl[f] = *(const bf16x8*)&sBl[ob];
    }
    #pragma unroll
    for (int i = 0; i < 4; ++i)
      #pragma unroll
      for (int j = 0; j < 4; ++j) {
        acc[i][j] = __builtin_amdgcn_mfma_f32_16x16x32_bf16(fa[i], fbh[j], acc[i][j], 0, 0, 0);
        acc[i][j] = __builtin_amdgcn_mfma_f32_16x16x32_bf16(fa[i], fbl[j], acc[i][j], 0, 0, 0);
      }
    __syncthreads();
  }

  // ---- epilogue: bias + relu, bf16 store ----
  #pragma unroll
  for (int j = 0; j < 4; ++j) {
    int gn = col0 + wc * 64 + j * 16 + cl;
    float bn = bias[gn];
    #pragma unroll
    for (int i = 0; i < 4; ++i) {
      f32x4 v = acc[i][j];
      #pragma unroll
      for (int r = 0; r < 4; ++r) {
        int gm = row0 + wr * 64 + i * 16 + sl * 4 + r;
        if (gm < N_NODES) C16[(size_t)gm * HID + gn] = rne_bf16(fmaxf(v[r] + bn, 0.f));
      }
    }
  }
}

// ---------------- pooling (mean + max per graph) from bf16 ----------------
__device__ inline int lower_bound_i(const int* a, int n, int v) {
  int lo = 0, hi = n;
  while (lo < hi) { int m = (lo + hi) >> 1; if (a[m] < v) lo = m + 1; else hi = m; }
  return lo;
}

__global__ __launch_bounds__(256)
void k_pool(const unsigned short* __restrict__ y16, const int* __restrict__ batch,
            float* __restrict__ g) {
  const int gi = blockIdx.x, t = threadIdx.x;
  const int start = lower_bound_i(batch, N_NODES, gi);
  const int end   = lower_bound_i(batch, N_NODES, gi + 1);
  float sum = 0.f, mx = 0.f;
  #pragma unroll 4
  for (int n = start; n < end; ++n) {
    float v = bf16_to_f32(y16[(size_t)n * HID + t]);
    sum += v; mx = fmaxf(mx, v);
  }
  int cnt = end - start;
  g[gi * 512 + t] = sum / (float)(cnt > 0 ? cnt : 1);
  g[gi * 512 + 256 + t] = mx;
}

// ---------------- classifier head ----------------
__global__ __launch_bounds__(256)
void k_cls(const float* __restrict__ g, const float* __restrict__ Wc1,
           const float* __restrict__ bc1, const float* __restrict__ Wc2,
           const float* __restrict__ bc2, float* __restrict__ out) {
  const int gi = blockIdx.x, t = threadIdx.x;
  __shared__ float sg[512];
  __shared__ float sh[256];
  sg[t] = g[gi * 512 + t];
  sg[256 + t] = g[gi * 512 + 256 + t];
  __syncthreads();
  float a = bc1[t];
  #pragma unroll 8
  for (int k = 0; k < 512; ++k) a = fmaf(sg[k], Wc1[k * HID + t], a);
  sh[t] = fmaxf(a, 0.f);
  __syncthreads();
  if (t < 2) {
    float o = bc2[t];
    for (int k = 0; k < 256; ++k) o = fmaf(sh[k], Wc2[k * 2 + t], o);
    out[gi * 2 + t] = o;
  }
}

// ---------------- launch ----------------
extern "C" void kernel_launch(void* const* d_in, const int* in_sizes, int n_in,
                              void* d_out, int out_size, void* d_ws, size_t ws_size,
                              hipStream_t stream) {
  const int*   x_ids = (const int*)d_in[0];
  const int*   ei    = (const int*)d_in[1];
  const int*   batch = (const int*)d_in[2];
  const float* emb   = (const float*)d_in[3];
  const float* W0 = (const float*)d_in[4];  const float* b0 = (const float*)d_in[5];
  const float* W1 = (const float*)d_in[6];  const float* b1 = (const float*)d_in[7];
  const float* W2 = (const float*)d_in[8];  const float* b2 = (const float*)d_in[9];
  const float* W3 = (const float*)d_in[10]; const float* b3 = (const float*)d_in[11];
  const float* Wc1 = (const float*)d_in[12]; const float* bc1 = (const float*)d_in[13];
  const float* Wc2 = (const float*)d_in[14]; const float* bc2 = (const float*)d_in[15];
  float* out = (float*)d_out;
  const int* src = ei;
  const int* dst = ei + N_EDGES;

  char* ws = (char*)d_ws;
  size_t o = 0;
  auto alloc = [&](size_t bytes) -> char* {
    char* p = ws + o; o += (bytes + 255) & ~(size_t)255; return p;
  };
  unsigned short* y16  = (unsigned short*)alloc((size_t)N_NODES * HID * 2);
  unsigned short* aggA = (unsigned short*)alloc((size_t)N_NODES * HID * 2);
  float* dis   = (float*)alloc((size_t)N_NODES * 4);
  int*   indeg = (int*)  alloc((size_t)N_NODES * 4);
  int*   off   = (int*)  alloc((size_t)(N_NODES + 1) * 4);
  int*   cur   = (int*)  alloc((size_t)(N_NODES + 1) * 4);
  int*   bsum  = (int*)  alloc((size_t)(NB_SCAN + 1) * 4);
  int2*  csre  = (int2*) alloc((size_t)N_EDGES * 8);
  int2*  csre0 = (int2*) alloc((size_t)N_EDGES * 8);
  unsigned short* emb16 = (unsigned short*)alloc((size_t)VOCAB * EMBD * 2);
  unsigned short* wbuf  = (unsigned short*)alloc((size_t)458752 * 2);
  float* gf    = (float*)alloc((size_t)N_GRAPHS * 512 * 4);
  (void)ws_size; (void)in_sizes; (void)n_in; (void)out_size;

  unsigned short* wt0h = wbuf;            unsigned short* wt0l = wbuf + 32768;
  unsigned short* wt1h = wbuf + 65536;    unsigned short* wt1l = wbuf + 131072;
  unsigned short* wt2h = wbuf + 196608;   unsigned short* wt2l = wbuf + 262144;
  unsigned short* wt3h = wbuf + 327680;   unsigned short* wt3l = wbuf + 393216;

  hipMemsetAsync(indeg, 0, (size_t)N_NODES * 4, stream);
  k_indeg<<<N_EDGES / 256, 256, 0, stream>>>(dst, indeg);
  k_scan1<<<NB_SCAN, 1024, 0, stream>>>(indeg, off, bsum, dis);
  k_scan2<<<1, 64, 0, stream>>>(bsum);
  k_scan3<<<NB_SCAN, 1024, 0, stream>>>(off, cur, bsum);
  k_fill<<<N_EDGES / 256, 256, 0, stream>>>(src, dst, x_ids, dis, cur, csre, csre0);
  // prep: emb16 + 4 weight transpose/splits, one kernel
  k_prep<<<(VOCAB * EMBD + EMBD * HID + 3 * HID * HID + 255) / 256, 256, 0, stream>>>(
      emb, emb16, W0, wt0h, wt0l, W1, wt1h, wt1l, W2, wt2h, wt2l, W3, wt3h, wt3l);

  dim3 ggrid((N_NODES + 127) / 128, 2);
  // layer 0 (K = 128): gather directly from L2-resident emb16
  k_agg0<<<N_NODES / 4, 256, 0, stream>>>(emb16, x_ids, dis, off, csre0, aggA);
  k_gemm_mfma<128><<<ggrid, 256, 0, stream>>>(aggA, wt0h, wt0l, b0, y16);
  // layers 1..3 (K = 256): gather bf16 activations
  k_agg16<<<N_NODES / 4, 256, 0, stream>>>(y16, dis, off, csre, aggA);
  k_gemm_mfma<256><<<ggrid, 256, 0, stream>>>(aggA, wt1h, wt1l, b1, y16);
  k_agg16<<<N_NODES / 4, 256, 0, stream>>>(y16, dis, off, csre, aggA);
  k_gemm_mfma<256><<<ggrid, 256, 0, stream>>>(aggA, wt2h, wt2l, b2, y16);
  k_agg16<<<N_NODES / 4, 256, 0, stream>>>(y16, dis, off, csre, aggA);
  k_gemm_mfma<256><<<ggrid, 256, 0, stream>>>(aggA, wt3h, wt3l, b3, y16);

  k_pool<<<N_GRAPHS, 256, 0, stream>>>(y16, batch, gf);
  k_cls<<<N_GRAPHS, 256, 0, stream>>>(gf, Wc1, bc1, Wc2, bc2, out);
}

// Round 10
// 950.604 us; speedup vs baseline: 2.1600x; 1.0297x over previous
//
#include <hip/hip_runtime.h>
#include <hip/hip_bf16.h>
#include <cstdint>
#include <cstddef>

#define N_NODES 100000
#define N_EDGES 1600000
#define EMBD 128
#define HID 256
#define N_GRAPHS 128
#define VOCAB 1000
#define NB_SCAN 98   // ceil(N_NODES/1024)

typedef short bf16x8 __attribute__((ext_vector_type(8)));
typedef float f32x4 __attribute__((ext_vector_type(4)));
typedef float f32x2 __attribute__((ext_vector_type(2)));

__device__ inline unsigned short rne_bf16(float f) {
  unsigned u = __float_as_uint(f);
  return (unsigned short)((u + 0x7FFFu + ((u >> 16) & 1u)) >> 16);
}
__device__ inline float bf16_to_f32(unsigned short h) {
  return __uint_as_float(((unsigned)h) << 16);
}
__device__ inline void split_hl(float v, unsigned short& h, unsigned short& l) {
  h = rne_bf16(v);
  float hf = __uint_as_float(((unsigned)h) << 16);
  l = rne_bf16(v - hf);
}
__device__ inline f32x4 cvt4(uint2 v) {
  f32x4 r;
  r[0] = __uint_as_float(v.x << 16);
  r[1] = __uint_as_float(v.x & 0xFFFF0000u);
  r[2] = __uint_as_float(v.y << 16);
  r[3] = __uint_as_float(v.y & 0xFFFF0000u);
  return r;
}
__device__ inline f32x2 cvt2(unsigned v) {
  f32x2 r;
  r[0] = __uint_as_float(v << 16);
  r[1] = __uint_as_float(v & 0xFFFF0000u);
  return r;
}

// ---------------- CSR build ----------------
__global__ void k_indeg(const int* __restrict__ dst, int* __restrict__ indeg) {
  int e = blockIdx.x * 256 + threadIdx.x;
  if (e < N_EDGES) atomicAdd(&indeg[dst[e]], 1);
}

__global__ __launch_bounds__(1024)
void k_scan1(const int* __restrict__ indeg, int* __restrict__ off, int* __restrict__ bsum,
             float* __restrict__ dis) {
  __shared__ int s[1024];
  const int tid = threadIdx.x;
  int i = blockIdx.x * 1024 + tid;
  int v = (i < N_NODES) ? indeg[i] : 0;
  if (i < N_NODES) dis[i] = rsqrtf((float)(v + 1));   // fused degree-norm
  s[tid] = v; __syncthreads();
  #pragma unroll
  for (int ofs = 1; ofs < 1024; ofs <<= 1) {
    int t2 = (tid >= ofs) ? s[tid - ofs] : 0;
    __syncthreads();
    s[tid] += t2;
    __syncthreads();
  }
  if (i < N_NODES) off[i] = s[tid] - v;      // exclusive within block
  if (tid == 1023) bsum[blockIdx.x] = s[1023];
}

__global__ void k_scan2(int* __restrict__ bsum) {
  if (threadIdx.x == 0) {
    int a = 0;
    for (int i = 0; i < NB_SCAN; ++i) { int t = bsum[i]; bsum[i] = a; a += t; }
    bsum[NB_SCAN] = a;
  }
}

__global__ __launch_bounds__(1024)
void k_scan3(int* __restrict__ off, int* __restrict__ cur, const int* __restrict__ bsum) {
  int i = blockIdx.x * 1024 + threadIdx.x;
  if (i < N_NODES) { int v = off[i] + bsum[blockIdx.x]; off[i] = v; cur[i] = v; }
  if (i == 0) off[N_NODES] = bsum[NB_SCAN];
}

__global__ void k_fill(const int* __restrict__ src, const int* __restrict__ dst,
                       const int* __restrict__ ids, const float* __restrict__ dis,
                       int* __restrict__ cursor, int2* __restrict__ csre,
                       int2* __restrict__ csre0) {
  int e = blockIdx.x * 256 + threadIdx.x;
  if (e < N_EDGES) {
    int s = src[e];
    float ds = dis[s];
    int p = atomicAdd(&cursor[dst[e]], 1);
    csre[p]  = make_int2(s, __float_as_int(ds));
    csre0[p] = make_int2(ids[s], __float_as_int(ds));
  }
}

// ---------------- fused prep: emb->bf16 + W transpose/split ----------------
__global__ void k_prep(const float* __restrict__ emb, unsigned short* __restrict__ emb16,
                       const float* __restrict__ W0, unsigned short* __restrict__ w0h,
                       unsigned short* __restrict__ w0l,
                       const float* __restrict__ W1, unsigned short* __restrict__ w1h,
                       unsigned short* __restrict__ w1l,
                       const float* __restrict__ W2, unsigned short* __restrict__ w2h,
                       unsigned short* __restrict__ w2l,
                       const float* __restrict__ W3, unsigned short* __restrict__ w3h,
                       unsigned short* __restrict__ w3l) {
  int i = blockIdx.x * 256 + threadIdx.x;
  if (i < VOCAB * EMBD) { emb16[i] = rne_bf16(emb[i]); return; }
  i -= VOCAB * EMBD;
  unsigned short h, l;
  if (i < EMBD * HID) {               // W0: [128][256] -> [256][128] split
    int k = i >> 8, n = i & 255;
    split_hl(W0[i], h, l);
    w0h[n * EMBD + k] = h; w0l[n * EMBD + k] = l;
    return;
  }
  i -= EMBD * HID;
  if (i >= 3 * HID * HID) return;
  int w = i >> 16, j = i & 65535;     // W1..W3: [256][256] -> [256][256] split
  const float* Ws = (w == 0) ? W1 : (w == 1) ? W2 : W3;
  unsigned short* th = (w == 0) ? w1h : (w == 1) ? w2h : w3h;
  unsigned short* tl = (w == 0) ? w1l : (w == 1) ? w2l : w3l;
  int k = j >> 8, n = j & 255;
  split_hl(Ws[j], h, l);
  th[n * HID + k] = h; tl[n * HID + k] = l;
}

// ---------------- layer-0 aggregation: gather emb16 rows via ids (L2-hit) ----------------
__global__ __launch_bounds__(256)
void k_agg0(const unsigned short* __restrict__ emb16, const int* __restrict__ ids,
            const float* __restrict__ dis, const int* __restrict__ off,
            const int2* __restrict__ csre0, unsigned short* __restrict__ aggA) {
  const int lane = threadIdx.x & 63;
  const int node = blockIdx.x * 4 + (threadIdx.x >> 6);  // wave per node
  const float di = dis[node];
  unsigned sv = *((const unsigned*)(emb16 + (size_t)ids[node] * EMBD) + lane);
  f32x2 a0 = di * cvt2(sv);
  f32x2 a1 = (f32x2)0.f, a2 = (f32x2)0.f, a3 = (f32x2)0.f;
  const int e0 = off[node], e1 = off[node + 1];
  int e = e0;
  for (; e + 4 <= e1; e += 4) {
    int2 c0 = csre0[e], c1 = csre0[e + 1], c2 = csre0[e + 2], c3 = csre0[e + 3];
    unsigned v0 = *((const unsigned*)(emb16 + (size_t)c0.x * EMBD) + lane);
    unsigned v1 = *((const unsigned*)(emb16 + (size_t)c1.x * EMBD) + lane);
    unsigned v2 = *((const unsigned*)(emb16 + (size_t)c2.x * EMBD) + lane);
    unsigned v3 = *((const unsigned*)(emb16 + (size_t)c3.x * EMBD) + lane);
    a0 += __int_as_float(c0.y) * cvt2(v0);
    a1 += __int_as_float(c1.y) * cvt2(v1);
    a2 += __int_as_float(c2.y) * cvt2(v2);
    a3 += __int_as_float(c3.y) * cvt2(v3);
  }
  for (; e < e1; ++e) {
    int2 c0 = csre0[e];
    unsigned v0 = *((const unsigned*)(emb16 + (size_t)c0.x * EMBD) + lane);
    a0 += __int_as_float(c0.y) * cvt2(v0);
  }
  f32x2 r = di * ((a0 + a1) + (a2 + a3));
  size_t base = (size_t)node * EMBD + lane * 2;
  *(ushort2*)&aggA[base] = make_ushort2(rne_bf16(r[0]), rne_bf16(r[1]));
}

// ---------------- layers 1-3 aggregation: 8-deep unrolled gather ----------------
__global__ __launch_bounds__(256)
void k_agg16(const unsigned short* __restrict__ y16, const float* __restrict__ dis,
             const int* __restrict__ off, const int2* __restrict__ csre,
             unsigned short* __restrict__ aggA) {
  const int lane = threadIdx.x & 63;
  const int node = blockIdx.x * 4 + (threadIdx.x >> 6);  // wave per node
  const float di = dis[node];
  uint2 sv = *((const uint2*)(y16 + (size_t)node * HID) + lane);
  f32x4 a0 = di * cvt4(sv);
  f32x4 a1 = (f32x4)0.f, a2 = (f32x4)0.f, a3 = (f32x4)0.f;
  const int e0 = off[node], e1 = off[node + 1];
  int e = e0;
  for (; e + 8 <= e1; e += 8) {
    int2 c0 = csre[e],     c1 = csre[e + 1], c2 = csre[e + 2], c3 = csre[e + 3];
    int2 c4 = csre[e + 4], c5 = csre[e + 5], c6 = csre[e + 6], c7 = csre[e + 7];
    uint2 v0 = *((const uint2*)(y16 + (size_t)c0.x * HID) + lane);
    uint2 v1 = *((const uint2*)(y16 + (size_t)c1.x * HID) + lane);
    uint2 v2 = *((const uint2*)(y16 + (size_t)c2.x * HID) + lane);
    uint2 v3 = *((const uint2*)(y16 + (size_t)c3.x * HID) + lane);
    uint2 v4 = *((const uint2*)(y16 + (size_t)c4.x * HID) + lane);
    uint2 v5 = *((const uint2*)(y16 + (size_t)c5.x * HID) + lane);
    uint2 v6 = *((const uint2*)(y16 + (size_t)c6.x * HID) + lane);
    uint2 v7 = *((const uint2*)(y16 + (size_t)c7.x * HID) + lane);
    a0 += __int_as_float(c0.y) * cvt4(v0);
    a1 += __int_as_float(c1.y) * cvt4(v1);
    a2 += __int_as_float(c2.y) * cvt4(v2);
    a3 += __int_as_float(c3.y) * cvt4(v3);
    a0 += __int_as_float(c4.y) * cvt4(v4);
    a1 += __int_as_float(c5.y) * cvt4(v5);
    a2 += __int_as_float(c6.y) * cvt4(v6);
    a3 += __int_as_float(c7.y) * cvt4(v7);
  }
  for (; e + 4 <= e1; e += 4) {
    int2 c0 = csre[e], c1 = csre[e + 1], c2 = csre[e + 2], c3 = csre[e + 3];
    uint2 v0 = *((const uint2*)(y16 + (size_t)c0.x * HID) + lane);
    uint2 v1 = *((const uint2*)(y16 + (size_t)c1.x * HID) + lane);
    uint2 v2 = *((const uint2*)(y16 + (size_t)c2.x * HID) + lane);
    uint2 v3 = *((const uint2*)(y16 + (size_t)c3.x * HID) + lane);
    a0 += __int_as_float(c0.y) * cvt4(v0);
    a1 += __int_as_float(c1.y) * cvt4(v1);
    a2 += __int_as_float(c2.y) * cvt4(v2);
    a3 += __int_as_float(c3.y) * cvt4(v3);
  }
  for (; e < e1; ++e) {
    int2 c0 = csre[e];
    uint2 v0 = *((const uint2*)(y16 + (size_t)c0.x * HID) + lane);
    a0 += __int_as_float(c0.y) * cvt4(v0);
  }
  f32x4 r = di * ((a0 + a1) + (a2 + a3));
  size_t base = (size_t)node * HID + lane * 4;
  *(ushort4*)&aggA[base] = make_ushort4(rne_bf16(r[0]), rne_bf16(r[1]),
                                        rne_bf16(r[2]), rne_bf16(r[3]));
}

// ---------------- MFMA GEMM, 2-phase double-buffered staging ----------------
__device__ inline void gl_lds16(const void* g, void* l) {
  __builtin_amdgcn_global_load_lds((const __attribute__((address_space(1))) unsigned int*)g,
                                   (__attribute__((address_space(3))) unsigned int*)l,
                                   16, 0, 0);
}

template<int K>
__global__ __launch_bounds__(256)
void k_gemm_mfma(const unsigned short* __restrict__ Ah,
                 const unsigned short* __restrict__ Wh, const unsigned short* __restrict__ Wl,
                 const float* __restrict__ bias, unsigned short* __restrict__ C16) {
  // BM=128, BN=128, BK=32; 4 waves 2x2; per-wave 64x64 out; double-buffered LDS.
  __shared__ unsigned short sA[2][128 * 32];
  __shared__ unsigned short sBh[2][128 * 32];
  __shared__ unsigned short sBl[2][128 * 32];
  const int tid = threadIdx.x;
  const int lane = tid & 63;
  const int wid = tid >> 6;
  const int wr = wid >> 1, wc = wid & 1;
  const int row0 = blockIdx.x * 128;
  const int col0 = blockIdx.y * 128;
  const int cl = lane & 15;
  const int sl = lane >> 4;
  const int nt = K / 32;

  f32x4 acc[4][4];
  #pragma unroll
  for (int i = 0; i < 4; ++i)
    #pragma unroll
    for (int j = 0; j < 4; ++j) acc[i][j] = (f32x4)0.f;

  auto stage = [&](int b, int kt) {
    #pragma unroll
    for (int q = 0; q < 2; ++q) {
      int c = (wid * 2 + q) * 64 + lane;    // chunk id 0..511
      int row = c >> 2, slot = c & 3;
      int ss = slot ^ (row & 3);            // involution swizzle
      int ga = row0 + row; if (ga > N_NODES - 1) ga = N_NODES - 1;
      size_t aoff = (size_t)ga * K + kt + ss * 8;
      gl_lds16(Ah + aoff, &sA[b][(wid * 2 + q) * 512]);
      size_t boff = (size_t)(col0 + row) * K + kt + ss * 8;
      gl_lds16(Wh + boff, &sBh[b][(wid * 2 + q) * 512]);
      gl_lds16(Wl + boff, &sBl[b][(wid * 2 + q) * 512]);
    }
  };

  stage(0, 0);
  __syncthreads();                          // drain prologue staging

  for (int t = 0; t < nt; ++t) {
    const int cur = t & 1;
    if (t + 1 < nt) stage(cur ^ 1, (t + 1) * 32);   // prefetch flies under MFMA

    bf16x8 fa[4], fbh[4], fbl[4];
    #pragma unroll
    for (int f = 0; f < 4; ++f) {
      int ra = wr * 64 + f * 16 + cl;
      int oa = ra * 32 + ((sl ^ (ra & 3)) << 3);
      fa[f] = *(const bf16x8*)&sA[cur][oa];
      int rb = wc * 64 + f * 16 + cl;
      int ob = rb * 32 + ((sl ^ (rb & 3)) << 3);
      fbh[f] = *(const bf16x8*)&sBh[cur][ob];
      fbl[f] = *(const bf16x8*)&sBl[cur][ob];
    }
    #pragma unroll
    for (int i = 0; i < 4; ++i)
      #pragma unroll
      for (int j = 0; j < 4; ++j) {
        acc[i][j] = __builtin_amdgcn_mfma_f32_16x16x32_bf16(fa[i], fbh[j], acc[i][j], 0, 0, 0);
        acc[i][j] = __builtin_amdgcn_mfma_f32_16x16x32_bf16(fa[i], fbl[j], acc[i][j], 0, 0, 0);
      }
    __syncthreads();                        // drains prefetch + protects buffer reuse
  }

  // ---- epilogue: bias + relu, bf16 store ----
  #pragma unroll
  for (int j = 0; j < 4; ++j) {
    int gn = col0 + wc * 64 + j * 16 + cl;
    float bn = bias[gn];
    #pragma unroll
    for (int i = 0; i < 4; ++i) {
      f32x4 v = acc[i][j];
      #pragma unroll
      for (int r = 0; r < 4; ++r) {
        int gm = row0 + wr * 64 + i * 16 + sl * 4 + r;
        if (gm < N_NODES) C16[(size_t)gm * HID + gn] = rne_bf16(fmaxf(v[r] + bn, 0.f));
      }
    }
  }
}

// ---------------- pooling: 4 row-chunks per graph, atomic combine ----------------
__device__ inline int lower_bound_i(const int* a, int n, int v) {
  int lo = 0, hi = n;
  while (lo < hi) { int m = (lo + hi) >> 1; if (a[m] < v) lo = m + 1; else hi = m; }
  return lo;
}

__global__ __launch_bounds__(256)
void k_pool(const unsigned short* __restrict__ y16, const int* __restrict__ batch,
            float* __restrict__ gsum, float* __restrict__ gmax) {
  const int gi = blockIdx.x, ck = blockIdx.y, t = threadIdx.x;
  const int start = lower_bound_i(batch, N_NODES, gi);
  const int end   = lower_bound_i(batch, N_NODES, gi + 1);
  const int len = end - start;
  const int c0 = start + (len * ck) / 4;
  const int c1 = start + (len * (ck + 1)) / 4;
  float sum = 0.f, mx = 0.f;     // post-relu >= 0
  #pragma unroll 4
  for (int n = c0; n < c1; ++n) {
    float v = bf16_to_f32(y16[(size_t)n * HID + t]);
    sum += v; mx = fmaxf(mx, v);
  }
  if (c0 < c1) {
    atomicAdd(&gsum[gi * HID + t], sum);
    atomicMax((int*)&gmax[gi * HID + t], __float_as_int(mx));  // valid: mx >= 0
  }
}

// ---------------- classifier head ----------------
__global__ __launch_bounds__(256)
void k_cls(const float* __restrict__ gsum, const float* __restrict__ gmax,
           const int* __restrict__ batch,
           const float* __restrict__ Wc1, const float* __restrict__ bc1,
           const float* __restrict__ Wc2, const float* __restrict__ bc2,
           float* __restrict__ out) {
  const int gi = blockIdx.x, t = threadIdx.x;
  __shared__ float sg[512];
  __shared__ float sh[256];
  const int start = lower_bound_i(batch, N_NODES, gi);
  const int end   = lower_bound_i(batch, N_NODES, gi + 1);
  const float rcnt = 1.f / (float)((end - start) > 0 ? (end - start) : 1);
  sg[t] = gsum[gi * HID + t] * rcnt;
  sg[256 + t] = gmax[gi * HID + t];
  __syncthreads();
  float a = bc1[t];
  #pragma unroll 8
  for (int k = 0; k < 512; ++k) a = fmaf(sg[k], Wc1[k * HID + t], a);
  sh[t] = fmaxf(a, 0.f);
  __syncthreads();
  if (t < 2) {
    float o = bc2[t];
    for (int k = 0; k < 256; ++k) o = fmaf(sh[k], Wc2[k * 2 + t], o);
    out[gi * 2 + t] = o;
  }
}

// ---------------- launch ----------------
extern "C" void kernel_launch(void* const* d_in, const int* in_sizes, int n_in,
                              void* d_out, int out_size, void* d_ws, size_t ws_size,
                              hipStream_t stream) {
  const int*   x_ids = (const int*)d_in[0];
  const int*   ei    = (const int*)d_in[1];
  const int*   batch = (const int*)d_in[2];
  const float* emb   = (const float*)d_in[3];
  const float* W0 = (const float*)d_in[4];  const float* b0 = (const float*)d_in[5];
  const float* W1 = (const float*)d_in[6];  const float* b1 = (const float*)d_in[7];
  const float* W2 = (const float*)d_in[8];  const float* b2 = (const float*)d_in[9];
  const float* W3 = (const float*)d_in[10]; const float* b3 = (const float*)d_in[11];
  const float* Wc1 = (const float*)d_in[12]; const float* bc1 = (const float*)d_in[13];
  const float* Wc2 = (const float*)d_in[14]; const float* bc2 = (const float*)d_in[15];
  float* out = (float*)d_out;
  const int* src = ei;
  const int* dst = ei + N_EDGES;

  char* ws = (char*)d_ws;
  size_t o = 0;
  auto alloc = [&](size_t bytes) -> char* {
    char* p = ws + o; o += (bytes + 255) & ~(size_t)255; return p;
  };
  unsigned short* y16  = (unsigned short*)alloc((size_t)N_NODES * HID * 2);
  unsigned short* aggA = (unsigned short*)alloc((size_t)N_NODES * HID * 2);
  float* dis   = (float*)alloc((size_t)N_NODES * 4);
  int*   indeg = (int*)  alloc((size_t)N_NODES * 4);
  int*   off   = (int*)  alloc((size_t)(N_NODES + 1) * 4);
  int*   cur   = (int*)  alloc((size_t)(N_NODES + 1) * 4);
  int*   bsum  = (int*)  alloc((size_t)(NB_SCAN + 1) * 4);
  int2*  csre  = (int2*) alloc((size_t)N_EDGES * 8);
  int2*  csre0 = (int2*) alloc((size_t)N_EDGES * 8);
  unsigned short* emb16 = (unsigned short*)alloc((size_t)VOCAB * EMBD * 2);
  unsigned short* wbuf  = (unsigned short*)alloc((size_t)458752 * 2);
  float* gsum  = (float*)alloc((size_t)N_GRAPHS * HID * 4);
  float* gmax  = (float*)alloc((size_t)N_GRAPHS * HID * 4);
  (void)ws_size; (void)in_sizes; (void)n_in; (void)out_size;

  unsigned short* wt0h = wbuf;            unsigned short* wt0l = wbuf + 32768;
  unsigned short* wt1h = wbuf + 65536;    unsigned short* wt1l = wbuf + 131072;
  unsigned short* wt2h = wbuf + 196608;   unsigned short* wt2l = wbuf + 262144;
  unsigned short* wt3h = wbuf + 327680;   unsigned short* wt3l = wbuf + 393216;

  hipMemsetAsync(indeg, 0, (size_t)N_NODES * 4, stream);
  hipMemsetAsync(gsum, 0, (size_t)N_GRAPHS * HID * 4 * 2 + 256, stream); // gsum+gmax (contiguous allocs)
  k_indeg<<<N_EDGES / 256, 256, 0, stream>>>(dst, indeg);
  k_scan1<<<NB_SCAN, 1024, 0, stream>>>(indeg, off, bsum, dis);
  k_scan2<<<1, 64, 0, stream>>>(bsum);
  k_scan3<<<NB_SCAN, 1024, 0, stream>>>(off, cur, bsum);
  k_fill<<<N_EDGES / 256, 256, 0, stream>>>(src, dst, x_ids, dis, cur, csre, csre0);
  k_prep<<<(VOCAB * EMBD + EMBD * HID + 3 * HID * HID + 255) / 256, 256, 0, stream>>>(
      emb, emb16, W0, wt0h, wt0l, W1, wt1h, wt1l, W2, wt2h, wt2l, W3, wt3h, wt3l);

  dim3 ggrid((N_NODES + 127) / 128, 2);
  // layer 0 (K = 128): gather directly from L2-resident emb16
  k_agg0<<<N_NODES / 4, 256, 0, stream>>>(emb16, x_ids, dis, off, csre0, aggA);
  k_gemm_mfma<128><<<ggrid, 256, 0, stream>>>(aggA, wt0h, wt0l, b0, y16);
  // layers 1..3 (K = 256): gather bf16 activations
  k_agg16<<<N_NODES / 4, 256, 0, stream>>>(y16, dis, off, csre, aggA);
  k_gemm_mfma<256><<<ggrid, 256, 0, stream>>>(aggA, wt1h, wt1l, b1, y16);
  k_agg16<<<N_NODES / 4, 256, 0, stream>>>(y16, dis, off, csre, aggA);
  k_gemm_mfma<256><<<ggrid, 256, 0, stream>>>(aggA, wt2h, wt2l, b2, y16);
  k_agg16<<<N_NODES / 4, 256, 0, stream>>>(y16, dis, off, csre, aggA);
  k_gemm_mfma<256><<<ggrid, 256, 0, stream>>>(aggA, wt3h, wt3l, b3, y16);

  dim3 pgrid(N_GRAPHS, 4);
  k_pool<<<pgrid, 256, 0, stream>>>(y16, batch, gsum, gmax);
  k_cls<<<N_GRAPHS, 256, 0, stream>>>(gsum, gmax, batch, Wc1, bc1, Wc2, bc2, out);
}